// Round 1
// baseline (4312.925 us; speedup 1.0000x reference)
//
#include <hip/hip_runtime.h>
#include <math.h>

// Problem constants (fixed shapes from setup_inputs)
constexpr int B_  = 4;
constexpr int H_  = 64;
constexpr int W_  = 64;
constexpr int C_  = 96;
constexpr int L_  = H_ * W_;        // 4096
constexpr int DI  = 192;            // 2*C
constexpr int K_  = 4;
constexpr int NST = 16;
constexpr int R_  = 6;
constexpr int M_  = B_ * L_;        // 16384 rows

// ---------------- helpers ----------------
__device__ __forceinline__ float wave_sum64(float v) {
#pragma unroll
  for (int off = 1; off < 64; off <<= 1) v += __shfl_xor(v, off, 64);
  return v;
}

// spatial position read/written by direction k at scan step l
__device__ __forceinline__ int pos_kl(int k, int l) {
  int ll = (k >= 2) ? (L_ - 1 - l) : l;
  int i = ll & 63;      // row
  int j = ll >> 6;      // diag index
  int col = ((k & 1) == 0) ? ((i + j) & 63) : ((j - i) & 63);
  return (i << 6) + col;
}

__device__ __forceinline__ float silu_f(float x) {
  return x / (1.f + __expf(-x));
}

// ---------------- LN over C=96, one wave per row ----------------
__global__ __launch_bounds__(256) void ln96_kernel(const float* __restrict__ in,
    const float* __restrict__ g, const float* __restrict__ b,
    float* __restrict__ out) {
  int wave = blockIdx.x * 4 + (threadIdx.x >> 6);
  int lane = threadIdx.x & 63;
  const float* rp = in + (size_t)wave * C_;
  float v0 = rp[lane];
  float v1 = (lane < C_ - 64) ? rp[lane + 64] : 0.f;
  float s  = wave_sum64(v0 + v1);
  float s2 = wave_sum64(v0 * v0 + v1 * v1);
  float mean = s * (1.f / C_);
  float var  = s2 * (1.f / C_) - mean * mean;
  float inv  = rsqrtf(var + 1e-5f);
  float* op = out + (size_t)wave * C_;
  op[lane] = (v0 - mean) * inv * g[lane] + b[lane];
  if (lane < C_ - 64) op[lane + 64] = (v1 - mean) * inv * g[lane + 64] + b[lane + 64];
}

// ---------------- in_proj: xz = h @ W^T, W (384,96); split into xin/z ----------------
__global__ __launch_bounds__(384) void gemm_in_kernel(const float* __restrict__ h,
    const float* __restrict__ w, float* __restrict__ xin, float* __restrict__ z) {
  __shared__ float hs[8][C_];
  int row0 = blockIdx.x * 8;
  for (int t = threadIdx.x; t < 8 * C_; t += 384)
    hs[t / C_][t % C_] = h[(size_t)(row0 + t / C_) * C_ + (t % C_)];
  __syncthreads();
  int j = threadIdx.x;  // 0..383
  float acc[8];
#pragma unroll
  for (int r = 0; r < 8; r++) acc[r] = 0.f;
  const float* wr = w + (size_t)j * C_;
  for (int c = 0; c < C_; c++) {
    float wv = wr[c];
#pragma unroll
    for (int r = 0; r < 8; r++) acc[r] += wv * hs[r][c];
  }
#pragma unroll
  for (int r = 0; r < 8; r++) {
    size_t row = row0 + r;
    if (j < DI) xin[row * DI + j] = acc[r];
    else        z[row * DI + (j - DI)] = acc[r];
  }
}

// ---------------- depthwise 3x3 conv (NHWC) + SiLU ----------------
__global__ __launch_bounds__(192) void conv_silu_kernel(const float* __restrict__ xin,
    const float* __restrict__ cw, const float* __restrict__ cb, float* __restrict__ imgT) {
  int p = blockIdx.x;          // b*L + i*W + j
  int b = p >> 12;
  int ij = p & 4095;
  int i = ij >> 6, j = ij & 63;
  int c = threadIdx.x;
  float acc = cb[c];
#pragma unroll
  for (int di = -1; di <= 1; di++) {
    int ii = i + di;
    if (ii < 0 || ii >= H_) continue;
#pragma unroll
    for (int dj = -1; dj <= 1; dj++) {
      int jj = j + dj;
      if (jj < 0 || jj >= W_) continue;
      acc += xin[((size_t)b * L_ + ii * W_ + jj) * DI + c] * cw[c * 9 + (di + 1) * 3 + (dj + 1)];
    }
  }
  imgT[(size_t)p * DI + c] = silu_f(acc);
}

// ---------------- x_dbl projections -> dts6 (B,K,L,6), BsT/CsT (B,K,L,16) ----------------
__global__ __launch_bounds__(256) void xdbl_kernel(const float* __restrict__ imgT,
    const float* __restrict__ xpw, float* __restrict__ dts6,
    float* __restrict__ BsT, float* __restrict__ CsT) {
  __shared__ float xs[8][193];   // pad to break bank conflicts
  int blk = blockIdx.x;          // b*K*(L/8) + k*(L/8) + lt
  int lt = blk % (L_ / 8);
  int bk = blk / (L_ / 8);
  int k = bk % K_, b = bk / K_;
  int l0 = lt * 8;
  for (int t = threadIdx.x; t < 8 * DI; t += 256) {
    int li = t / DI, d = t % DI;
    xs[li][d] = imgT[(size_t)b * L_ * DI + (size_t)pos_kl(k, l0 + li) * DI + d];
  }
  __syncthreads();
  for (int t = threadIdx.x; t < 8 * 38; t += 256) {
    int li = t & 7, c = t >> 3;
    const float* wr = xpw + (size_t)(k * 38 + c) * DI;
    float acc = 0.f;
    for (int d = 0; d < DI; d++) acc += xs[li][d] * wr[d];
    size_t base = (size_t)(b * K_ + k) * L_ + (l0 + li);
    if (c < R_)            dts6[base * R_ + c] = acc;
    else if (c < R_ + NST) BsT[base * NST + (c - R_)] = acc;
    else                   CsT[base * NST + (c - R_ - NST)] = acc;
  }
}

// ---------------- y_pre init: sum_k Ds[k,d] * imgT (skip term) ----------------
__global__ __launch_bounds__(256) void ypre_init_kernel(const float* __restrict__ imgT,
    const float* __restrict__ Ds, float* __restrict__ y_pre) {
  int idx = blockIdx.x * 256 + threadIdx.x;
  int d = idx % DI;
  float ds = Ds[d] + Ds[DI + d] + Ds[2 * DI + d] + Ds[3 * DI + d];
  y_pre[idx] = imgT[idx] * ds;
}

// ---------------- selective scan: 16 lanes per (b,k,d); scatter via atomicAdd ----------------
__global__ __launch_bounds__(64) void scan_kernel(const float* __restrict__ imgT,
    const float* __restrict__ dts6, const float* __restrict__ BsT,
    const float* __restrict__ CsT, const float* __restrict__ dtw,
    const float* __restrict__ dtb, const float* __restrict__ A_logs,
    float* __restrict__ y_pre) {
  int blk = blockIdx.x;        // b*(K*48) + k*48 + dg
  int dg = blk % 48;
  int bk = blk / 48;
  int k = bk % K_, b = bk / K_;
  int dl = threadIdx.x >> 4, n = threadIdx.x & 15;
  int d = dg * 4 + dl;
  float A    = -__expf(A_logs[(size_t)(k * DI + d) * NST + n]);
  float bias = dtb[k * DI + d];
  float w[R_];
#pragma unroll
  for (int r = 0; r < R_; r++) w[r] = dtw[(size_t)(k * DI + d) * R_ + r];
  const float* dts_bk = dts6 + (size_t)(b * K_ + k) * L_ * R_;
  const float* Bs_bk  = BsT  + (size_t)(b * K_ + k) * L_ * NST;
  const float* Cs_bk  = CsT  + (size_t)(b * K_ + k) * L_ * NST;
  const float* img_b  = imgT + (size_t)b * L_ * DI;
  float* yp_b = y_pre + (size_t)b * L_ * DI;
  float h = 0.f;
  for (int l = 0; l < L_; l++) {
    int p = pos_kl(k, l);
    float u = img_b[(size_t)p * DI + d];
    const float* dr = dts_bk + (size_t)l * R_;
    float s = bias;
#pragma unroll
    for (int r = 0; r < R_; r++) s += w[r] * dr[r];
    float delta = (s > 20.f) ? s : log1pf(__expf(s));
    float Bn = Bs_bk[(size_t)l * NST + n];
    float Cn = Cs_bk[(size_t)l * NST + n];
    float dA = __expf(delta * A);
    h = dA * h + (delta * u) * Bn;
    float y = h * Cn;
    y += __shfl_xor(y, 1, 16);
    y += __shfl_xor(y, 2, 16);
    y += __shfl_xor(y, 4, 16);
    y += __shfl_xor(y, 8, 16);
    if (n == 0) atomicAdd(&yp_b[(size_t)p * DI + d], y);
  }
}

// ---------------- LN over Di=192 + multiply by silu(z), in-place into z ----------------
__global__ __launch_bounds__(256) void ln_mulz_kernel(const float* __restrict__ y_pre,
    const float* __restrict__ g, const float* __restrict__ bb, float* __restrict__ z) {
  int wave = blockIdx.x * 4 + (threadIdx.x >> 6);
  int lane = threadIdx.x & 63;
  const float* rp = y_pre + (size_t)wave * DI;
  float v0 = rp[lane], v1 = rp[lane + 64], v2 = rp[lane + 128];
  float s  = wave_sum64(v0 + v1 + v2);
  float s2 = wave_sum64(v0 * v0 + v1 * v1 + v2 * v2);
  float mean = s * (1.f / DI);
  float var  = s2 * (1.f / DI) - mean * mean;
  float inv  = rsqrtf(var + 1e-5f);
  float* zp = z + (size_t)wave * DI;
  float vv[3] = {v0, v1, v2};
#pragma unroll
  for (int q = 0; q < 3; q++) {
    int c = lane + 64 * q;
    float zv = zp[c];
    zp[c] = ((vv[q] - mean) * inv * g[c] + bb[c]) * silu_f(zv);
  }
}

// ---------------- out_proj (96x192) + residual add ----------------
__global__ __launch_bounds__(128) void outproj_kernel(const float* __restrict__ yz,
    const float* __restrict__ opw, const float* __restrict__ x, float* __restrict__ x_res) {
  __shared__ float ys[8][DI];
  int row0 = blockIdx.x * 8;
  for (int t = threadIdx.x; t < 8 * DI; t += 128)
    ys[t / DI][t % DI] = yz[(size_t)(row0 + t / DI) * DI + (t % DI)];
  __syncthreads();
  int j = threadIdx.x;
  if (j < C_) {
    float acc[8];
#pragma unroll
    for (int r = 0; r < 8; r++) acc[r] = 0.f;
    const float* wr = opw + (size_t)j * DI;
    for (int d = 0; d < DI; d++) {
      float wv = wr[d];
#pragma unroll
      for (int r = 0; r < 8; r++) acc[r] += wv * ys[r][d];
    }
#pragma unroll
    for (int r = 0; r < 8; r++) {
      size_t row = row0 + r;
      x_res[row * C_ + j] = x[row * C_ + j] + acc[r];
    }
  }
}

// ---------------- KAN linear: silu-base GEMM + B-spline GEMM ----------------
__global__ __launch_bounds__(128) void kan_kernel(const float* __restrict__ in,
    const float* __restrict__ bw, const float* __restrict__ sw, float* __restrict__ out) {
  __shared__ float sil[8][C_];
  __shared__ float bs[8][C_][8];
  int row0 = blockIdx.x * 8;
  for (int t = threadIdx.x; t < 8 * C_; t += 128) {
    int r = t / C_, c = t % C_;
    float x = in[(size_t)(row0 + r) * C_ + c];
    sil[r][c] = silu_f(x);
    float bb[11];
#pragma unroll
    for (int i2 = 0; i2 < 11; i2++) {
      float g0 = 0.4f * i2 - 2.2f;
      float g1 = 0.4f * i2 - 1.8f;
      bb[i2] = (x >= g0 && x < g1) ? 1.f : 0.f;
    }
#pragma unroll
    for (int k2 = 1; k2 <= 3; k2++) {
      float invd = 1.f / (0.4f * k2);
#pragma unroll
      for (int i2 = 0; i2 + k2 < 11; i2++) {
        float gi   = 0.4f * i2 - 2.2f;
        float gik1 = 0.4f * (i2 + k2 + 1) - 2.2f;
        bb[i2] = (x - gi) * invd * bb[i2] + (gik1 - x) * invd * bb[i2 + 1];
      }
    }
#pragma unroll
    for (int q = 0; q < 8; q++) bs[r][c][q] = bb[q];
  }
  __syncthreads();
  int j = threadIdx.x;
  if (j < C_) {
    float acc[8];
#pragma unroll
    for (int r = 0; r < 8; r++) acc[r] = 0.f;
    const float* bwr = bw + (size_t)j * C_;
    for (int c = 0; c < C_; c++) {
      float wv = bwr[c];
#pragma unroll
      for (int r = 0; r < 8; r++) acc[r] += wv * sil[r][c];
    }
    const float* swr = sw + (size_t)j * (C_ * 8);
    for (int cq = 0; cq < C_ * 8; cq++) {
      float wv = swr[cq];
      int c = cq >> 3, q = cq & 7;
#pragma unroll
      for (int r = 0; r < 8; r++) acc[r] += wv * bs[r][c][q];
    }
#pragma unroll
    for (int r = 0; r < 8; r++) out[(size_t)(row0 + r) * C_ + j] = acc[r];
  }
}

// ---------------- depthwise 3x3 + BN-ish scale + ReLU (+ optional residual) ----------------
__global__ __launch_bounds__(128) void dwbn_kernel(const float* __restrict__ t,
    const float* __restrict__ w, const float* __restrict__ bias,
    const float* __restrict__ gamma, const float* __restrict__ beta,
    const float* __restrict__ addres, float* __restrict__ out) {
  int p = blockIdx.x;
  int b = p >> 12;
  int ij = p & 4095;
  int i = ij >> 6, j = ij & 63;
  int c = threadIdx.x;
  if (c >= C_) return;
  float acc = bias[c];
#pragma unroll
  for (int di = -1; di <= 1; di++) {
    int ii = i + di;
    if (ii < 0 || ii >= H_) continue;
#pragma unroll
    for (int dj = -1; dj <= 1; dj++) {
      int jj = j + dj;
      if (jj < 0 || jj >= W_) continue;
      acc += t[((size_t)b * L_ + ii * W_ + jj) * C_ + c] * w[c * 9 + (di + 1) * 3 + (dj + 1)];
    }
  }
  float v = acc * (gamma[c] * rsqrtf(1.f + 1e-5f)) + beta[c];
  v = fmaxf(v, 0.f);
  if (addres != nullptr) v += addres[(size_t)p * C_ + c];
  out[(size_t)p * C_ + c] = v;
}

// ---------------- host launcher ----------------
extern "C" void kernel_launch(void* const* d_in, const int* in_sizes, int n_in,
                              void* d_out, int out_size, void* d_ws, size_t ws_size,
                              hipStream_t stream) {
  const float* x         = (const float*)d_in[0];
  const float* norm1_g   = (const float*)d_in[3];
  const float* norm1_b   = (const float*)d_in[4];
  const float* in_proj_w = (const float*)d_in[5];
  const float* conv_w    = (const float*)d_in[6];
  const float* conv_b    = (const float*)d_in[7];
  const float* x_proj_w  = (const float*)d_in[8];
  const float* dt_w      = (const float*)d_in[9];
  const float* dt_b      = (const float*)d_in[10];
  const float* A_logs    = (const float*)d_in[11];
  const float* Ds        = (const float*)d_in[12];
  const float* out_ng    = (const float*)d_in[13];
  const float* out_nb    = (const float*)d_in[14];
  const float* out_proj_w= (const float*)d_in[15];
  const float* norm2_g   = (const float*)d_in[16];
  const float* norm2_b   = (const float*)d_in[17];
  const float* fc1_bw    = (const float*)d_in[18];
  const float* fc1_sw    = (const float*)d_in[19];
  const float* fc2_bw    = (const float*)d_in[20];
  const float* fc2_sw    = (const float*)d_in[21];
  const float* fc3_bw    = (const float*)d_in[22];
  const float* fc3_sw    = (const float*)d_in[23];
  const float* dw1_w     = (const float*)d_in[24];
  const float* dw1_b     = (const float*)d_in[25];
  const float* dw1_g     = (const float*)d_in[26];
  const float* dw1_be    = (const float*)d_in[27];
  const float* dw2_w     = (const float*)d_in[28];
  const float* dw2_b     = (const float*)d_in[29];
  const float* dw2_g     = (const float*)d_in[30];
  const float* dw2_be    = (const float*)d_in[31];
  const float* dw3_w     = (const float*)d_in[32];
  const float* dw3_b     = (const float*)d_in[33];
  const float* dw3_g     = (const float*)d_in[34];
  const float* dw3_be    = (const float*)d_in[35];

  float* ws = (float*)d_ws;
  float* h_buf   = ws;                       // M*96
  float* xin_buf = h_buf + (size_t)M_ * C_;  // M*192
  float* z_buf   = xin_buf + (size_t)M_ * DI;
  float* imgT    = z_buf + (size_t)M_ * DI;
  float* dts6    = imgT + (size_t)M_ * DI;                 // B*K*L*6
  float* BsT     = dts6 + (size_t)B_ * K_ * L_ * R_;       // B*K*L*16
  float* CsT     = BsT + (size_t)B_ * K_ * L_ * NST;
  float* y_pre   = CsT + (size_t)B_ * K_ * L_ * NST;       // M*192
  float* x_res   = y_pre + (size_t)M_ * DI;                // M*96
  float* t_a     = x_res + (size_t)M_ * C_;
  float* t_b     = t_a + (size_t)M_ * C_;

  // 1. LN1
  ln96_kernel<<<M_ / 4, 256, 0, stream>>>(x, norm1_g, norm1_b, h_buf);
  // 2. in_proj -> xin, z
  gemm_in_kernel<<<M_ / 8, 384, 0, stream>>>(h_buf, in_proj_w, xin_buf, z_buf);
  // 3. dwconv + silu -> imgT (NHWC)
  conv_silu_kernel<<<M_, 192, 0, stream>>>(xin_buf, conv_w, conv_b, imgT);
  // 4. x_dbl projections
  xdbl_kernel<<<B_ * K_ * (L_ / 8), 256, 0, stream>>>(imgT, x_proj_w, dts6, BsT, CsT);
  // 5. skip-term init
  ypre_init_kernel<<<(M_ * DI) / 256, 256, 0, stream>>>(imgT, Ds, y_pre);
  // 6. selective scan (4 directions) with fused scatter
  scan_kernel<<<B_ * K_ * 48, 64, 0, stream>>>(imgT, dts6, BsT, CsT, dt_w, dt_b, A_logs, y_pre);
  // 7. out-norm LN + silu(z) gate (in-place into z)
  ln_mulz_kernel<<<M_ / 4, 256, 0, stream>>>(y_pre, out_ng, out_nb, z_buf);
  // 8. out_proj + residual
  outproj_kernel<<<M_ / 8, 128, 0, stream>>>(z_buf, out_proj_w, x, x_res);
  // 9. LN2
  ln96_kernel<<<M_ / 4, 256, 0, stream>>>(x_res, norm2_g, norm2_b, h_buf);
  // 10. KAN / dw-bn-relu chain
  kan_kernel<<<M_ / 8, 128, 0, stream>>>(h_buf, fc1_bw, fc1_sw, t_a);
  dwbn_kernel<<<M_, 128, 0, stream>>>(t_a, dw1_w, dw1_b, dw1_g, dw1_be, nullptr, t_b);
  kan_kernel<<<M_ / 8, 128, 0, stream>>>(t_b, fc2_bw, fc2_sw, t_a);
  dwbn_kernel<<<M_, 128, 0, stream>>>(t_a, dw2_w, dw2_b, dw2_g, dw2_be, nullptr, t_b);
  kan_kernel<<<M_ / 8, 128, 0, stream>>>(t_b, fc3_bw, fc3_sw, t_a);
  dwbn_kernel<<<M_, 128, 0, stream>>>(t_a, dw3_w, dw3_b, dw3_g, dw3_be, x_res, (float*)d_out);
}

// Round 2
// 1075.621 us; speedup vs baseline: 4.0097x; 4.0097x over previous
//
#include <hip/hip_runtime.h>
#include <math.h>

// Problem constants (fixed shapes from setup_inputs)
constexpr int B_  = 4;
constexpr int H_  = 64;
constexpr int W_  = 64;
constexpr int C_  = 96;
constexpr int L_  = H_ * W_;        // 4096
constexpr int DI  = 192;            // 2*C
constexpr int K_  = 4;
constexpr int NST = 16;
constexpr int R_  = 6;
constexpr int M_  = B_ * L_;        // 16384 rows

// chunked-scan params
constexpr int NCH = 64;             // number of chunks along L
constexpr int CL  = 64;             // chunk length (NCH*CL == L_)
constexpr int DG  = DI / 16;        // 12 d-groups of 16 channels

// ---------------- helpers ----------------
__device__ __forceinline__ float wave_sum64(float v) {
#pragma unroll
  for (int off = 1; off < 64; off <<= 1) v += __shfl_xor(v, off, 64);
  return v;
}

// spatial position read/written by direction k at scan step l
__device__ __forceinline__ int pos_kl(int k, int l) {
  int ll = (k >= 2) ? (L_ - 1 - l) : l;
  int i = ll & 63;      // row
  int j = ll >> 6;      // diag index
  int col = ((k & 1) == 0) ? ((i + j) & 63) : ((j - i) & 63);
  return (i << 6) + col;
}

__device__ __forceinline__ float silu_f(float x) {
  return x / (1.f + __expf(-x));
}

__device__ __forceinline__ float softplus_f(float s) {
  return fmaxf(s, 0.f) + log1pf(__expf(-fabsf(s)));
}

// ---------------- LN over C=96, one wave per row ----------------
__global__ __launch_bounds__(256) void ln96_kernel(const float* __restrict__ in,
    const float* __restrict__ g, const float* __restrict__ b,
    float* __restrict__ out) {
  int wave = blockIdx.x * 4 + (threadIdx.x >> 6);
  int lane = threadIdx.x & 63;
  const float* rp = in + (size_t)wave * C_;
  float v0 = rp[lane];
  float v1 = (lane < C_ - 64) ? rp[lane + 64] : 0.f;
  float s  = wave_sum64(v0 + v1);
  float s2 = wave_sum64(v0 * v0 + v1 * v1);
  float mean = s * (1.f / C_);
  float var  = s2 * (1.f / C_) - mean * mean;
  float inv  = rsqrtf(var + 1e-5f);
  float* op = out + (size_t)wave * C_;
  op[lane] = (v0 - mean) * inv * g[lane] + b[lane];
  if (lane < C_ - 64) op[lane + 64] = (v1 - mean) * inv * g[lane + 64] + b[lane + 64];
}

// ---------------- in_proj: xz = h @ W^T, W (384,96); split into xin/z ----------------
__global__ __launch_bounds__(384) void gemm_in_kernel(const float* __restrict__ h,
    const float* __restrict__ w, float* __restrict__ xin, float* __restrict__ z) {
  __shared__ float hs[8][C_];
  int row0 = blockIdx.x * 8;
  for (int t = threadIdx.x; t < 8 * C_; t += 384)
    hs[t / C_][t % C_] = h[(size_t)(row0 + t / C_) * C_ + (t % C_)];
  __syncthreads();
  int j = threadIdx.x;  // 0..383
  float acc[8];
#pragma unroll
  for (int r = 0; r < 8; r++) acc[r] = 0.f;
  const float* wr = w + (size_t)j * C_;
  for (int c = 0; c < C_; c++) {
    float wv = wr[c];
#pragma unroll
    for (int r = 0; r < 8; r++) acc[r] += wv * hs[r][c];
  }
#pragma unroll
  for (int r = 0; r < 8; r++) {
    size_t row = row0 + r;
    if (j < DI) xin[row * DI + j] = acc[r];
    else        z[row * DI + (j - DI)] = acc[r];
  }
}

// ---------------- depthwise 3x3 conv (NHWC) + SiLU ----------------
__global__ __launch_bounds__(192) void conv_silu_kernel(const float* __restrict__ xin,
    const float* __restrict__ cw, const float* __restrict__ cb, float* __restrict__ imgT) {
  int p = blockIdx.x;          // b*L + i*W + j
  int b = p >> 12;
  int ij = p & 4095;
  int i = ij >> 6, j = ij & 63;
  int c = threadIdx.x;
  float acc = cb[c];
#pragma unroll
  for (int di = -1; di <= 1; di++) {
    int ii = i + di;
    if (ii < 0 || ii >= H_) continue;
#pragma unroll
    for (int dj = -1; dj <= 1; dj++) {
      int jj = j + dj;
      if (jj < 0 || jj >= W_) continue;
      acc += xin[((size_t)b * L_ + ii * W_ + jj) * DI + c] * cw[c * 9 + (di + 1) * 3 + (dj + 1)];
    }
  }
  imgT[(size_t)p * DI + c] = silu_f(acc);
}

// ---------------- x_dbl projections -> delta (B,K,L,DI), BsT/CsT (B,K,L,16) ----------------
__global__ __launch_bounds__(256) void xdbl_kernel(const float* __restrict__ imgT,
    const float* __restrict__ xpw, const float* __restrict__ dtw,
    const float* __restrict__ dtb, float* __restrict__ delta,
    float* __restrict__ BsT, float* __restrict__ CsT) {
  __shared__ float xs[8][193];   // pad to break bank conflicts
  __shared__ float dts_s[8][6];
  int blk = blockIdx.x;          // b*K*(L/8) + k*(L/8) + lt
  int lt = blk % (L_ / 8);
  int bk = blk / (L_ / 8);
  int k = bk % K_, b = bk / K_;
  int l0 = lt * 8;
  for (int t = threadIdx.x; t < 8 * DI; t += 256) {
    int li = t / DI, d = t % DI;
    xs[li][d] = imgT[(size_t)b * L_ * DI + (size_t)pos_kl(k, l0 + li) * DI + d];
  }
  __syncthreads();
  for (int t = threadIdx.x; t < 8 * 38; t += 256) {
    int li = t & 7, c = t >> 3;
    const float* wr = xpw + (size_t)(k * 38 + c) * DI;
    float acc = 0.f;
    for (int d = 0; d < DI; d++) acc += xs[li][d] * wr[d];
    size_t base = (size_t)(b * K_ + k) * L_ + (l0 + li);
    if (c < R_)            dts_s[li][c] = acc;
    else if (c < R_ + NST) BsT[base * NST + (c - R_)] = acc;
    else                   CsT[base * NST + (c - R_ - NST)] = acc;
  }
  __syncthreads();
  // delta[b][k][l][d] = softplus(dtw[k,d,:] . dts + dtb[k,d])
  for (int t = threadIdx.x; t < 8 * DI; t += 256) {
    int li = t / DI, d = t % DI;
    float s = dtb[k * DI + d];
    const float* wv = dtw + (size_t)(k * DI + d) * R_;
#pragma unroll
    for (int r = 0; r < R_; r++) s += wv[r] * dts_s[li][r];
    delta[((size_t)(b * K_ + k) * L_ + (l0 + li)) * DI + d] = softplus_f(s);
  }
}

// ---------------- y_pre init: sum_k Ds[k,d] * imgT (skip term) ----------------
__global__ __launch_bounds__(256) void ypre_init_kernel(const float* __restrict__ imgT,
    const float* __restrict__ Ds, float* __restrict__ y_pre) {
  int idx = blockIdx.x * 256 + threadIdx.x;
  int d = idx % DI;
  float ds = Ds[d] + Ds[DI + d] + Ds[2 * DI + d] + Ds[3 * DI + d];
  y_pre[idx] = imgT[idx] * ds;
}

// ---------------- chunked scan pass 1: per-chunk local scan from h=0 ----------------
// grid: ((b*K+k)*DG + dg)*NCH + c ; block 256 = 16 d x 16 n
__global__ __launch_bounds__(256) void scan1_kernel(const float* __restrict__ imgT,
    const float* __restrict__ delta, const float* __restrict__ BsT,
    const float* __restrict__ A_logs, float* __restrict__ hend,
    float* __restrict__ aprod) {
  __shared__ float u_s[CL][16];
  __shared__ float dl_s[CL][16];
  __shared__ float bs_s[CL][16];
  int blk = blockIdx.x;
  int c = blk % NCH;
  int tmp = blk / NCH;
  int dg = tmp % DG;
  tmp /= DG;
  int k = tmp % K_, b = tmp / K_;
  int l0 = c * CL;
  int d0 = dg * 16;
  const float* img_b  = imgT  + (size_t)b * L_ * DI;
  const float* del_bk = delta + (size_t)(b * K_ + k) * L_ * DI;
  const float* Bs_bk  = BsT   + (size_t)(b * K_ + k) * L_ * NST;
  for (int t = threadIdx.x; t < CL * 16; t += 256) {
    int li = t >> 4, dd = t & 15;
    int l = l0 + li;
    int p = pos_kl(k, l);
    u_s[li][dd]  = img_b[(size_t)p * DI + d0 + dd];
    dl_s[li][dd] = del_bk[(size_t)l * DI + d0 + dd];
    bs_s[li][dd] = Bs_bk[(size_t)l * NST + dd];
  }
  __syncthreads();
  int dl_ = threadIdx.x >> 4, n = threadIdx.x & 15;
  int d = d0 + dl_;
  float A = -__expf(A_logs[(size_t)(k * DI + d) * NST + n]);
  float h = 0.f, ap = 1.f;
  for (int l = 0; l < CL; l++) {
    float dlt = dl_s[l][dl_];
    float dA = __expf(dlt * A);
    h = dA * h + (dlt * u_s[l][dl_]) * bs_s[l][n];
    ap *= dA;
  }
  size_t idx = (((size_t)(b * K_ + k) * NCH + c) * DI + d) * NST + n;
  hend[idx]  = h;
  aprod[idx] = ap;
}

// ---------------- carry sweep over chunks (in-place: hend becomes carry_in) ----------------
// grid: (b*K+k)*DG + dg ; block 256 = 16 d x 16 n
__global__ __launch_bounds__(256) void scan_carry_kernel(float* __restrict__ hend,
    const float* __restrict__ aprod) {
  int blk = blockIdx.x;
  int dg = blk % DG;
  int tmp = blk / DG;
  int k = tmp % K_, b = tmp / K_;
  const size_t DNS = (size_t)DI * NST;
  size_t base = (size_t)(b * K_ + k) * NCH * DNS + (size_t)dg * 16 * NST + threadIdx.x;
  float hv = hend[base], av = aprod[base];
  float carry = 0.f;
  for (int c = 0; c < NCH; c++) {
    size_t idx = base + (size_t)c * DNS;
    float hv_n = 0.f, av_n = 0.f;
    if (c + 1 < NCH) { hv_n = hend[idx + DNS]; av_n = aprod[idx + DNS]; }
    hend[idx] = carry;                 // carry entering chunk c
    carry = av * carry + hv;
    hv = hv_n; av = av_n;
  }
}

// ---------------- chunked scan pass 2: re-scan with true initial state, emit y ----------------
__global__ __launch_bounds__(256) void scan2_kernel(const float* __restrict__ imgT,
    const float* __restrict__ delta, const float* __restrict__ BsT,
    const float* __restrict__ CsT, const float* __restrict__ A_logs,
    const float* __restrict__ carry_in, float* __restrict__ y_pre) {
  __shared__ float u_s[CL][16];
  __shared__ float dl_s[CL][16];
  __shared__ float bs_s[CL][16];
  __shared__ float cs_s[CL][16];
  __shared__ float y_s[CL][16];
  int blk = blockIdx.x;
  int c = blk % NCH;
  int tmp = blk / NCH;
  int dg = tmp % DG;
  tmp /= DG;
  int k = tmp % K_, b = tmp / K_;
  int l0 = c * CL;
  int d0 = dg * 16;
  const float* img_b  = imgT  + (size_t)b * L_ * DI;
  const float* del_bk = delta + (size_t)(b * K_ + k) * L_ * DI;
  const float* Bs_bk  = BsT   + (size_t)(b * K_ + k) * L_ * NST;
  const float* Cs_bk  = CsT   + (size_t)(b * K_ + k) * L_ * NST;
  for (int t = threadIdx.x; t < CL * 16; t += 256) {
    int li = t >> 4, dd = t & 15;
    int l = l0 + li;
    int p = pos_kl(k, l);
    u_s[li][dd]  = img_b[(size_t)p * DI + d0 + dd];
    dl_s[li][dd] = del_bk[(size_t)l * DI + d0 + dd];
    bs_s[li][dd] = Bs_bk[(size_t)l * NST + dd];
    cs_s[li][dd] = Cs_bk[(size_t)l * NST + dd];
  }
  __syncthreads();
  int dl_ = threadIdx.x >> 4, n = threadIdx.x & 15;
  int d = d0 + dl_;
  float A = -__expf(A_logs[(size_t)(k * DI + d) * NST + n]);
  size_t cidx = (((size_t)(b * K_ + k) * NCH + c) * DI + d) * NST + n;
  float h = carry_in[cidx];
  for (int l = 0; l < CL; l++) {
    float dlt = dl_s[l][dl_];
    float dA = __expf(dlt * A);
    h = dA * h + (dlt * u_s[l][dl_]) * bs_s[l][n];
    float y = h * cs_s[l][n];
    y += __shfl_xor(y, 1, 16);
    y += __shfl_xor(y, 2, 16);
    y += __shfl_xor(y, 4, 16);
    y += __shfl_xor(y, 8, 16);
    if (n == 0) y_s[l][dl_] = y;
  }
  __syncthreads();
  float* yp_b = y_pre + (size_t)b * L_ * DI;
  for (int t = threadIdx.x; t < CL * 16; t += 256) {
    int li = t >> 4, dd = t & 15;
    int p = pos_kl(k, l0 + li);
    atomicAdd(&yp_b[(size_t)p * DI + d0 + dd], y_s[li][dd]);
  }
}

// ---------------- LN over Di=192 + multiply by silu(z), in-place into z ----------------
__global__ __launch_bounds__(256) void ln_mulz_kernel(const float* __restrict__ y_pre,
    const float* __restrict__ g, const float* __restrict__ bb, float* __restrict__ z) {
  int wave = blockIdx.x * 4 + (threadIdx.x >> 6);
  int lane = threadIdx.x & 63;
  const float* rp = y_pre + (size_t)wave * DI;
  float v0 = rp[lane], v1 = rp[lane + 64], v2 = rp[lane + 128];
  float s  = wave_sum64(v0 + v1 + v2);
  float s2 = wave_sum64(v0 * v0 + v1 * v1 + v2 * v2);
  float mean = s * (1.f / DI);
  float var  = s2 * (1.f / DI) - mean * mean;
  float inv  = rsqrtf(var + 1e-5f);
  float* zp = z + (size_t)wave * DI;
  float vv[3] = {v0, v1, v2};
#pragma unroll
  for (int q = 0; q < 3; q++) {
    int c = lane + 64 * q;
    float zv = zp[c];
    zp[c] = ((vv[q] - mean) * inv * g[c] + bb[c]) * silu_f(zv);
  }
}

// ---------------- out_proj (96x192) + residual add ----------------
__global__ __launch_bounds__(128) void outproj_kernel(const float* __restrict__ yz,
    const float* __restrict__ opw, const float* __restrict__ x, float* __restrict__ x_res) {
  __shared__ float ys[8][DI];
  int row0 = blockIdx.x * 8;
  for (int t = threadIdx.x; t < 8 * DI; t += 128)
    ys[t / DI][t % DI] = yz[(size_t)(row0 + t / DI) * DI + (t % DI)];
  __syncthreads();
  int j = threadIdx.x;
  if (j < C_) {
    float acc[8];
#pragma unroll
    for (int r = 0; r < 8; r++) acc[r] = 0.f;
    const float* wr = opw + (size_t)j * DI;
    for (int d = 0; d < DI; d++) {
      float wv = wr[d];
#pragma unroll
      for (int r = 0; r < 8; r++) acc[r] += wv * ys[r][d];
    }
#pragma unroll
    for (int r = 0; r < 8; r++) {
      size_t row = row0 + r;
      x_res[row * C_ + j] = x[row * C_ + j] + acc[r];
    }
  }
}

// ---------------- KAN linear: silu-base GEMM + B-spline GEMM ----------------
__global__ __launch_bounds__(128) void kan_kernel(const float* __restrict__ in,
    const float* __restrict__ bw, const float* __restrict__ sw, float* __restrict__ out) {
  __shared__ float sil[8][C_];
  __shared__ float bs[8][C_][8];
  int row0 = blockIdx.x * 8;
  for (int t = threadIdx.x; t < 8 * C_; t += 128) {
    int r = t / C_, c = t % C_;
    float x = in[(size_t)(row0 + r) * C_ + c];
    sil[r][c] = silu_f(x);
    float bb[11];
#pragma unroll
    for (int i2 = 0; i2 < 11; i2++) {
      float g0 = 0.4f * i2 - 2.2f;
      float g1 = 0.4f * i2 - 1.8f;
      bb[i2] = (x >= g0 && x < g1) ? 1.f : 0.f;
    }
#pragma unroll
    for (int k2 = 1; k2 <= 3; k2++) {
      float invd = 1.f / (0.4f * k2);
#pragma unroll
      for (int i2 = 0; i2 + k2 < 11; i2++) {
        float gi   = 0.4f * i2 - 2.2f;
        float gik1 = 0.4f * (i2 + k2 + 1) - 2.2f;
        bb[i2] = (x - gi) * invd * bb[i2] + (gik1 - x) * invd * bb[i2 + 1];
      }
    }
#pragma unroll
    for (int q = 0; q < 8; q++) bs[r][c][q] = bb[q];
  }
  __syncthreads();
  int j = threadIdx.x;
  if (j < C_) {
    float acc[8];
#pragma unroll
    for (int r = 0; r < 8; r++) acc[r] = 0.f;
    const float* bwr = bw + (size_t)j * C_;
    for (int c = 0; c < C_; c++) {
      float wv = bwr[c];
#pragma unroll
      for (int r = 0; r < 8; r++) acc[r] += wv * sil[r][c];
    }
    const float* swr = sw + (size_t)j * (C_ * 8);
    for (int cq = 0; cq < C_ * 8; cq++) {
      float wv = swr[cq];
      int c = cq >> 3, q = cq & 7;
#pragma unroll
      for (int r = 0; r < 8; r++) acc[r] += wv * bs[r][c][q];
    }
#pragma unroll
    for (int r = 0; r < 8; r++) out[(size_t)(row0 + r) * C_ + j] = acc[r];
  }
}

// ---------------- depthwise 3x3 + BN-ish scale + ReLU (+ optional residual) ----------------
__global__ __launch_bounds__(128) void dwbn_kernel(const float* __restrict__ t,
    const float* __restrict__ w, const float* __restrict__ bias,
    const float* __restrict__ gamma, const float* __restrict__ beta,
    const float* __restrict__ addres, float* __restrict__ out) {
  int p = blockIdx.x;
  int b = p >> 12;
  int ij = p & 4095;
  int i = ij >> 6, j = ij & 63;
  int c = threadIdx.x;
  if (c >= C_) return;
  float acc = bias[c];
#pragma unroll
  for (int di = -1; di <= 1; di++) {
    int ii = i + di;
    if (ii < 0 || ii >= H_) continue;
#pragma unroll
    for (int dj = -1; dj <= 1; dj++) {
      int jj = j + dj;
      if (jj < 0 || jj >= W_) continue;
      acc += t[((size_t)b * L_ + ii * W_ + jj) * C_ + c] * w[c * 9 + (di + 1) * 3 + (dj + 1)];
    }
  }
  float v = acc * (gamma[c] * rsqrtf(1.f + 1e-5f)) + beta[c];
  v = fmaxf(v, 0.f);
  if (addres != nullptr) v += addres[(size_t)p * C_ + c];
  out[(size_t)p * C_ + c] = v;
}

// ---------------- host launcher ----------------
extern "C" void kernel_launch(void* const* d_in, const int* in_sizes, int n_in,
                              void* d_out, int out_size, void* d_ws, size_t ws_size,
                              hipStream_t stream) {
  const float* x         = (const float*)d_in[0];
  const float* norm1_g   = (const float*)d_in[3];
  const float* norm1_b   = (const float*)d_in[4];
  const float* in_proj_w = (const float*)d_in[5];
  const float* conv_w    = (const float*)d_in[6];
  const float* conv_b    = (const float*)d_in[7];
  const float* x_proj_w  = (const float*)d_in[8];
  const float* dt_w      = (const float*)d_in[9];
  const float* dt_b      = (const float*)d_in[10];
  const float* A_logs    = (const float*)d_in[11];
  const float* Ds        = (const float*)d_in[12];
  const float* out_ng    = (const float*)d_in[13];
  const float* out_nb    = (const float*)d_in[14];
  const float* out_proj_w= (const float*)d_in[15];
  const float* norm2_g   = (const float*)d_in[16];
  const float* norm2_b   = (const float*)d_in[17];
  const float* fc1_bw    = (const float*)d_in[18];
  const float* fc1_sw    = (const float*)d_in[19];
  const float* fc2_bw    = (const float*)d_in[20];
  const float* fc2_sw    = (const float*)d_in[21];
  const float* fc3_bw    = (const float*)d_in[22];
  const float* fc3_sw    = (const float*)d_in[23];
  const float* dw1_w     = (const float*)d_in[24];
  const float* dw1_b     = (const float*)d_in[25];
  const float* dw1_g     = (const float*)d_in[26];
  const float* dw1_be    = (const float*)d_in[27];
  const float* dw2_w     = (const float*)d_in[28];
  const float* dw2_b     = (const float*)d_in[29];
  const float* dw2_g     = (const float*)d_in[30];
  const float* dw2_be    = (const float*)d_in[31];
  const float* dw3_w     = (const float*)d_in[32];
  const float* dw3_b     = (const float*)d_in[33];
  const float* dw3_g     = (const float*)d_in[34];
  const float* dw3_be    = (const float*)d_in[35];

  float* ws = (float*)d_ws;
  float* h_buf   = ws;                       // M*96
  float* xin_buf = h_buf + (size_t)M_ * C_;  // M*192  (aliased by aprod after conv)
  float* z_buf   = xin_buf + (size_t)M_ * DI;
  float* imgT    = z_buf + (size_t)M_ * DI;
  float* BsT     = imgT + (size_t)M_ * DI;                 // B*K*L*16
  float* CsT     = BsT + (size_t)B_ * K_ * L_ * NST;
  float* y_pre   = CsT + (size_t)B_ * K_ * L_ * NST;       // M*192
  float* x_res   = y_pre + (size_t)M_ * DI;                // M*96
  float* t_a     = x_res + (size_t)M_ * C_;                // M*96 (hend part 1)
  float* t_b     = t_a + (size_t)M_ * C_;                  // M*96 (hend part 2)
  float* delta   = t_b + (size_t)M_ * C_;                  // B*K*L*DI (50 MB)
  // aliases (lifetimes disjoint):
  float* aprod   = xin_buf;   // B*K*NCH*DI*NST = M*DI floats, xin dead after conv
  float* hend    = t_a;       // B*K*NCH*DI*NST = 2*M*C floats, t_a/t_b used only post-scan

  // 1. LN1
  ln96_kernel<<<M_ / 4, 256, 0, stream>>>(x, norm1_g, norm1_b, h_buf);
  // 2. in_proj -> xin, z
  gemm_in_kernel<<<M_ / 8, 384, 0, stream>>>(h_buf, in_proj_w, xin_buf, z_buf);
  // 3. dwconv + silu -> imgT (NHWC)
  conv_silu_kernel<<<M_, 192, 0, stream>>>(xin_buf, conv_w, conv_b, imgT);
  // 4. x_dbl projections + delta precompute
  xdbl_kernel<<<B_ * K_ * (L_ / 8), 256, 0, stream>>>(imgT, x_proj_w, dt_w, dt_b,
                                                      delta, BsT, CsT);
  // 5. skip-term init
  ypre_init_kernel<<<(M_ * DI) / 256, 256, 0, stream>>>(imgT, Ds, y_pre);
  // 6. chunked selective scan
  scan1_kernel<<<B_ * K_ * DG * NCH, 256, 0, stream>>>(imgT, delta, BsT, A_logs,
                                                       hend, aprod);
  scan_carry_kernel<<<B_ * K_ * DG, 256, 0, stream>>>(hend, aprod);
  scan2_kernel<<<B_ * K_ * DG * NCH, 256, 0, stream>>>(imgT, delta, BsT, CsT, A_logs,
                                                       hend, y_pre);
  // 7. out-norm LN + silu(z) gate (in-place into z)
  ln_mulz_kernel<<<M_ / 4, 256, 0, stream>>>(y_pre, out_ng, out_nb, z_buf);
  // 8. out_proj + residual
  outproj_kernel<<<M_ / 8, 128, 0, stream>>>(z_buf, out_proj_w, x, x_res);
  // 9. LN2
  ln96_kernel<<<M_ / 4, 256, 0, stream>>>(x_res, norm2_g, norm2_b, h_buf);
  // 10. KAN / dw-bn-relu chain
  kan_kernel<<<M_ / 8, 128, 0, stream>>>(h_buf, fc1_bw, fc1_sw, t_a);
  dwbn_kernel<<<M_, 128, 0, stream>>>(t_a, dw1_w, dw1_b, dw1_g, dw1_be, nullptr, t_b);
  kan_kernel<<<M_ / 8, 128, 0, stream>>>(t_b, fc2_bw, fc2_sw, t_a);
  dwbn_kernel<<<M_, 128, 0, stream>>>(t_a, dw2_w, dw2_b, dw2_g, dw2_be, nullptr, t_b);
  kan_kernel<<<M_ / 8, 128, 0, stream>>>(t_b, fc3_bw, fc3_sw, t_a);
  dwbn_kernel<<<M_, 128, 0, stream>>>(t_a, dw3_w, dw3_b, dw3_g, dw3_be, x_res, (float*)d_out);
}

// Round 3
// 941.133 us; speedup vs baseline: 4.5827x; 1.1429x over previous
//
#include <hip/hip_runtime.h>
#include <math.h>

// Problem constants (fixed shapes from setup_inputs)
constexpr int B_  = 4;
constexpr int H_  = 64;
constexpr int W_  = 64;
constexpr int C_  = 96;
constexpr int L_  = H_ * W_;        // 4096
constexpr int DI  = 192;            // 2*C
constexpr int K_  = 4;
constexpr int NST = 16;
constexpr int R_  = 6;
constexpr int M_  = B_ * L_;        // 16384 rows

// chunked-scan params
constexpr int NCH = 64;             // number of chunks along L
constexpr int CL  = 64;             // chunk length (NCH*CL == L_)
constexpr int DG  = DI / 16;        // 12 d-groups of 16 (carry kernel tiling)

// ---------------- helpers ----------------
__device__ __forceinline__ float wave_sum64(float v) {
#pragma unroll
  for (int off = 1; off < 64; off <<= 1) v += __shfl_xor(v, off, 64);
  return v;
}

// spatial position read/written by direction k at scan step l
__device__ __forceinline__ int pos_kl(int k, int l) {
  int ll = (k >= 2) ? (L_ - 1 - l) : l;
  int i = ll & 63;      // row
  int j = ll >> 6;      // diag index
  int col = ((k & 1) == 0) ? ((i + j) & 63) : ((j - i) & 63);
  return (i << 6) + col;
}

__device__ __forceinline__ float silu_f(float x) {
  return x / (1.f + __expf(-x));
}

__device__ __forceinline__ float softplus_f(float s) {
  return fmaxf(s, 0.f) + log1pf(__expf(-fabsf(s)));
}

// ---------------- LN over C=96, one wave per row ----------------
__global__ __launch_bounds__(256) void ln96_kernel(const float* __restrict__ in,
    const float* __restrict__ g, const float* __restrict__ b,
    float* __restrict__ out) {
  int wave = blockIdx.x * 4 + (threadIdx.x >> 6);
  int lane = threadIdx.x & 63;
  const float* rp = in + (size_t)wave * C_;
  float v0 = rp[lane];
  float v1 = (lane < C_ - 64) ? rp[lane + 64] : 0.f;
  float s  = wave_sum64(v0 + v1);
  float s2 = wave_sum64(v0 * v0 + v1 * v1);
  float mean = s * (1.f / C_);
  float var  = s2 * (1.f / C_) - mean * mean;
  float inv  = rsqrtf(var + 1e-5f);
  float* op = out + (size_t)wave * C_;
  op[lane] = (v0 - mean) * inv * g[lane] + b[lane];
  if (lane < C_ - 64) op[lane + 64] = (v1 - mean) * inv * g[lane + 64] + b[lane + 64];
}

// ---------------- in_proj: xz = h @ W^T, W (384,96); split into xin/z ----------------
__global__ __launch_bounds__(384) void gemm_in_kernel(const float* __restrict__ h,
    const float* __restrict__ w, float* __restrict__ xin, float* __restrict__ z) {
  __shared__ float hs[8][C_];
  int row0 = blockIdx.x * 8;
  for (int t = threadIdx.x; t < 8 * C_; t += 384)
    hs[t / C_][t % C_] = h[(size_t)(row0 + t / C_) * C_ + (t % C_)];
  __syncthreads();
  int j = threadIdx.x;  // 0..383
  float acc[8];
#pragma unroll
  for (int r = 0; r < 8; r++) acc[r] = 0.f;
  const float* wr = w + (size_t)j * C_;
  for (int c = 0; c < C_; c++) {
    float wv = wr[c];
#pragma unroll
    for (int r = 0; r < 8; r++) acc[r] += wv * hs[r][c];
  }
#pragma unroll
  for (int r = 0; r < 8; r++) {
    size_t row = row0 + r;
    if (j < DI) xin[row * DI + j] = acc[r];
    else        z[row * DI + (j - DI)] = acc[r];
  }
}

// ---------------- depthwise 3x3 conv (NHWC) + SiLU ----------------
__global__ __launch_bounds__(192) void conv_silu_kernel(const float* __restrict__ xin,
    const float* __restrict__ cw, const float* __restrict__ cb, float* __restrict__ imgT) {
  int p = blockIdx.x;          // b*L + i*W + j
  int b = p >> 12;
  int ij = p & 4095;
  int i = ij >> 6, j = ij & 63;
  int c = threadIdx.x;
  float acc = cb[c];
#pragma unroll
  for (int di = -1; di <= 1; di++) {
    int ii = i + di;
    if (ii < 0 || ii >= H_) continue;
#pragma unroll
    for (int dj = -1; dj <= 1; dj++) {
      int jj = j + dj;
      if (jj < 0 || jj >= W_) continue;
      acc += xin[((size_t)b * L_ + ii * W_ + jj) * DI + c] * cw[c * 9 + (di + 1) * 3 + (dj + 1)];
    }
  }
  imgT[(size_t)p * DI + c] = silu_f(acc);
}

// ---------------- x_dbl projections -> delta (B,K,L,DI), BsT/CsT (B,K,L,16) ----------------
__global__ __launch_bounds__(256) void xdbl_kernel(const float* __restrict__ imgT,
    const float* __restrict__ xpw, const float* __restrict__ dtw,
    const float* __restrict__ dtb, float* __restrict__ delta,
    float* __restrict__ BsT, float* __restrict__ CsT) {
  __shared__ float xs[8][193];   // pad to break bank conflicts
  __shared__ float dts_s[8][6];
  int blk = blockIdx.x;          // b*K*(L/8) + k*(L/8) + lt
  int lt = blk % (L_ / 8);
  int bk = blk / (L_ / 8);
  int k = bk % K_, b = bk / K_;
  int l0 = lt * 8;
  for (int t = threadIdx.x; t < 8 * DI; t += 256) {
    int li = t / DI, d = t % DI;
    xs[li][d] = imgT[(size_t)b * L_ * DI + (size_t)pos_kl(k, l0 + li) * DI + d];
  }
  __syncthreads();
  for (int t = threadIdx.x; t < 8 * 38; t += 256) {
    int li = t & 7, c = t >> 3;
    const float* wr = xpw + (size_t)(k * 38 + c) * DI;
    float acc = 0.f;
    for (int d = 0; d < DI; d++) acc += xs[li][d] * wr[d];
    size_t base = (size_t)(b * K_ + k) * L_ + (l0 + li);
    if (c < R_)            dts_s[li][c] = acc;
    else if (c < R_ + NST) BsT[base * NST + (c - R_)] = acc;
    else                   CsT[base * NST + (c - R_ - NST)] = acc;
  }
  __syncthreads();
  // delta[b][k][l][d] = softplus(dtw[k,d,:] . dts + dtb[k,d])
  for (int t = threadIdx.x; t < 8 * DI; t += 256) {
    int li = t / DI, d = t % DI;
    float s = dtb[k * DI + d];
    const float* wv = dtw + (size_t)(k * DI + d) * R_;
#pragma unroll
    for (int r = 0; r < R_; r++) s += wv[r] * dts_s[li][r];
    delta[((size_t)(b * K_ + k) * L_ + (l0 + li)) * DI + d] = softplus_f(s);
  }
}

// ---------------- y_pre init: sum_k Ds[k,d] * imgT (skip term) ----------------
__global__ __launch_bounds__(256) void ypre_init_kernel(const float* __restrict__ imgT,
    const float* __restrict__ Ds, float* __restrict__ y_pre) {
  int idx = blockIdx.x * 256 + threadIdx.x;
  int d = idx % DI;
  float ds = Ds[d] + Ds[DI + d] + Ds[2 * DI + d] + Ds[3 * DI + d];
  y_pre[idx] = imgT[idx] * ds;
}

// ---------------- chunked scan pass 1: register-state local scan from h=0 ----------------
// grid: ((b*K+k)*NCH + c) ; block 192 threads = one per channel d; 16 states/thread
__global__ __launch_bounds__(192) void scan1_kernel(const float* __restrict__ imgT,
    const float* __restrict__ delta, const float* __restrict__ BsT,
    const float* __restrict__ A_logs, float* __restrict__ hend,
    float* __restrict__ aprod) {
  __shared__ float bs_s[CL][NST];
  int blk = blockIdx.x;
  int c = blk % NCH;
  int tmp = blk / NCH;
  int k = tmp % K_, b = tmp / K_;
  int l0 = c * CL;
  int d = threadIdx.x;
  const float* img_b  = imgT  + (size_t)b * L_ * DI;
  const float* del_bk = delta + (size_t)(b * K_ + k) * L_ * DI;
  const float* Bs_bk  = BsT   + (size_t)(b * K_ + k) * L_ * NST + (size_t)l0 * NST;
  for (int t = threadIdx.x; t < CL * NST; t += 192)
    bs_s[t >> 4][t & 15] = Bs_bk[t];
  float A[NST];
  {
    const float* ap = A_logs + (size_t)(k * DI + d) * NST;
#pragma unroll
    for (int n = 0; n < NST; n++) A[n] = -__expf(ap[n]);
  }
  __syncthreads();
  float h[NST];
#pragma unroll
  for (int n = 0; n < NST; n++) h[n] = 0.f;
  float sum_dlt = 0.f;
  // software prefetch of u/delta (coalesced over d)
  float u   = img_b[(size_t)pos_kl(k, l0) * DI + d];
  float dlt = del_bk[(size_t)l0 * DI + d];
  for (int l = 0; l < CL; l++) {
    float uc = u, dc = dlt;
    if (l + 1 < CL) {
      int pn = pos_kl(k, l0 + l + 1);
      u   = img_b[(size_t)pn * DI + d];
      dlt = del_bk[(size_t)(l0 + l + 1) * DI + d];
    }
    float du = dc * uc;
    sum_dlt += dc;
#pragma unroll
    for (int n = 0; n < NST; n++) {
      float dA = __expf(dc * A[n]);
      h[n] = dA * h[n] + du * bs_s[l][n];
    }
  }
  size_t idx = (((size_t)(b * K_ + k) * NCH + c) * DI + d) * NST;
  float4* hp  = (float4*)(hend + idx);
  float4* app = (float4*)(aprod + idx);
#pragma unroll
  for (int q = 0; q < 4; q++) {
    hp[q]  = make_float4(h[4 * q], h[4 * q + 1], h[4 * q + 2], h[4 * q + 3]);
    app[q] = make_float4(__expf(A[4 * q] * sum_dlt), __expf(A[4 * q + 1] * sum_dlt),
                         __expf(A[4 * q + 2] * sum_dlt), __expf(A[4 * q + 3] * sum_dlt));
  }
}

// ---------------- carry sweep over chunks (in-place: hend becomes carry_in) ----------------
// grid: (b*K+k)*DG + dg ; block 256 = 16 d x 16 n
__global__ __launch_bounds__(256) void scan_carry_kernel(float* __restrict__ hend,
    const float* __restrict__ aprod) {
  int blk = blockIdx.x;
  int dg = blk % DG;
  int tmp = blk / DG;
  int k = tmp % K_, b = tmp / K_;
  const size_t DNS = (size_t)DI * NST;
  size_t base = (size_t)(b * K_ + k) * NCH * DNS + (size_t)dg * 16 * NST + threadIdx.x;
  float hv = hend[base], av = aprod[base];
  float carry = 0.f;
  for (int c = 0; c < NCH; c++) {
    size_t idx = base + (size_t)c * DNS;
    float hv_n = 0.f, av_n = 0.f;
    if (c + 1 < NCH) { hv_n = hend[idx + DNS]; av_n = aprod[idx + DNS]; }
    hend[idx] = carry;                 // carry entering chunk c
    carry = av * carry + hv;
    hv = hv_n; av = av_n;
  }
}

// ---------------- chunked scan pass 2: register-state re-scan, emit y ----------------
// grid: ((b*K+k)*NCH + c) ; block 192 threads = one per channel d
__global__ __launch_bounds__(192) void scan2_kernel(const float* __restrict__ imgT,
    const float* __restrict__ delta, const float* __restrict__ BsT,
    const float* __restrict__ CsT, const float* __restrict__ A_logs,
    const float* __restrict__ carry_in, float* __restrict__ y_pre) {
  __shared__ float bs_s[CL][NST];
  __shared__ float cs_s[CL][NST];
  int blk = blockIdx.x;
  int c = blk % NCH;
  int tmp = blk / NCH;
  int k = tmp % K_, b = tmp / K_;
  int l0 = c * CL;
  int d = threadIdx.x;
  const float* img_b  = imgT  + (size_t)b * L_ * DI;
  const float* del_bk = delta + (size_t)(b * K_ + k) * L_ * DI;
  const float* Bs_bk  = BsT   + (size_t)(b * K_ + k) * L_ * NST + (size_t)l0 * NST;
  const float* Cs_bk  = CsT   + (size_t)(b * K_ + k) * L_ * NST + (size_t)l0 * NST;
  for (int t = threadIdx.x; t < CL * NST; t += 192) {
    bs_s[t >> 4][t & 15] = Bs_bk[t];
    cs_s[t >> 4][t & 15] = Cs_bk[t];
  }
  float A[NST];
  {
    const float* ap = A_logs + (size_t)(k * DI + d) * NST;
#pragma unroll
    for (int n = 0; n < NST; n++) A[n] = -__expf(ap[n]);
  }
  float h[NST];
  {
    size_t cidx = (((size_t)(b * K_ + k) * NCH + c) * DI + d) * NST;
    const float4* cp = (const float4*)(carry_in + cidx);
#pragma unroll
    for (int q = 0; q < 4; q++) {
      float4 v = cp[q];
      h[4 * q] = v.x; h[4 * q + 1] = v.y; h[4 * q + 2] = v.z; h[4 * q + 3] = v.w;
    }
  }
  __syncthreads();
  float* yp_b = y_pre + (size_t)b * L_ * DI;
  int pc = pos_kl(k, l0);
  float u   = img_b[(size_t)pc * DI + d];
  float dlt = del_bk[(size_t)l0 * DI + d];
  for (int l = 0; l < CL; l++) {
    float uc = u, dc = dlt;
    int p_cur = pc;
    if (l + 1 < CL) {
      pc = pos_kl(k, l0 + l + 1);
      u   = img_b[(size_t)pc * DI + d];
      dlt = del_bk[(size_t)(l0 + l + 1) * DI + d];
    }
    float du = dc * uc;
    float y = 0.f;
#pragma unroll
    for (int n = 0; n < NST; n++) {
      float dA = __expf(dc * A[n]);
      h[n] = dA * h[n] + du * bs_s[l][n];
      y += h[n] * cs_s[l][n];
    }
    atomicAdd(&yp_b[(size_t)p_cur * DI + d], y);   // coalesced across d
  }
}

// ---------------- LN over Di=192 + multiply by silu(z), in-place into z ----------------
__global__ __launch_bounds__(256) void ln_mulz_kernel(const float* __restrict__ y_pre,
    const float* __restrict__ g, const float* __restrict__ bb, float* __restrict__ z) {
  int wave = blockIdx.x * 4 + (threadIdx.x >> 6);
  int lane = threadIdx.x & 63;
  const float* rp = y_pre + (size_t)wave * DI;
  float v0 = rp[lane], v1 = rp[lane + 64], v2 = rp[lane + 128];
  float s  = wave_sum64(v0 + v1 + v2);
  float s2 = wave_sum64(v0 * v0 + v1 * v1 + v2 * v2);
  float mean = s * (1.f / DI);
  float var  = s2 * (1.f / DI) - mean * mean;
  float inv  = rsqrtf(var + 1e-5f);
  float* zp = z + (size_t)wave * DI;
  float vv[3] = {v0, v1, v2};
#pragma unroll
  for (int q = 0; q < 3; q++) {
    int c = lane + 64 * q;
    float zv = zp[c];
    zp[c] = ((vv[q] - mean) * inv * g[c] + bb[c]) * silu_f(zv);
  }
}

// ---------------- out_proj (96x192) + residual add ----------------
__global__ __launch_bounds__(128) void outproj_kernel(const float* __restrict__ yz,
    const float* __restrict__ opw, const float* __restrict__ x, float* __restrict__ x_res) {
  __shared__ float ys[8][DI];
  int row0 = blockIdx.x * 8;
  for (int t = threadIdx.x; t < 8 * DI; t += 128)
    ys[t / DI][t % DI] = yz[(size_t)(row0 + t / DI) * DI + (t % DI)];
  __syncthreads();
  int j = threadIdx.x;
  if (j < C_) {
    float acc[8];
#pragma unroll
    for (int r = 0; r < 8; r++) acc[r] = 0.f;
    const float* wr = opw + (size_t)j * DI;
    for (int d = 0; d < DI; d++) {
      float wv = wr[d];
#pragma unroll
      for (int r = 0; r < 8; r++) acc[r] += wv * ys[r][d];
    }
#pragma unroll
    for (int r = 0; r < 8; r++) {
      size_t row = row0 + r;
      x_res[row * C_ + j] = x[row * C_ + j] + acc[r];
    }
  }
}

// ---------------- KAN linear: silu-base GEMM + B-spline GEMM ----------------
__global__ __launch_bounds__(128) void kan_kernel(const float* __restrict__ in,
    const float* __restrict__ bw, const float* __restrict__ sw, float* __restrict__ out) {
  __shared__ float sil[8][C_];
  __shared__ float bs[8][C_][8];
  int row0 = blockIdx.x * 8;
  for (int t = threadIdx.x; t < 8 * C_; t += 128) {
    int r = t / C_, c = t % C_;
    float x = in[(size_t)(row0 + r) * C_ + c];
    sil[r][c] = silu_f(x);
    float bb[11];
#pragma unroll
    for (int i2 = 0; i2 < 11; i2++) {
      float g0 = 0.4f * i2 - 2.2f;
      float g1 = 0.4f * i2 - 1.8f;
      bb[i2] = (x >= g0 && x < g1) ? 1.f : 0.f;
    }
#pragma unroll
    for (int k2 = 1; k2 <= 3; k2++) {
      float invd = 1.f / (0.4f * k2);
#pragma unroll
      for (int i2 = 0; i2 + k2 < 11; i2++) {
        float gi   = 0.4f * i2 - 2.2f;
        float gik1 = 0.4f * (i2 + k2 + 1) - 2.2f;
        bb[i2] = (x - gi) * invd * bb[i2] + (gik1 - x) * invd * bb[i2 + 1];
      }
    }
#pragma unroll
    for (int q = 0; q < 8; q++) bs[r][c][q] = bb[q];
  }
  __syncthreads();
  int j = threadIdx.x;
  if (j < C_) {
    float acc[8];
#pragma unroll
    for (int r = 0; r < 8; r++) acc[r] = 0.f;
    const float* bwr = bw + (size_t)j * C_;
    for (int c = 0; c < C_; c++) {
      float wv = bwr[c];
#pragma unroll
      for (int r = 0; r < 8; r++) acc[r] += wv * sil[r][c];
    }
    const float* swr = sw + (size_t)j * (C_ * 8);
    for (int cq = 0; cq < C_ * 8; cq++) {
      float wv = swr[cq];
      int c = cq >> 3, q = cq & 7;
#pragma unroll
      for (int r = 0; r < 8; r++) acc[r] += wv * bs[r][c][q];
    }
#pragma unroll
    for (int r = 0; r < 8; r++) out[(size_t)(row0 + r) * C_ + j] = acc[r];
  }
}

// ---------------- depthwise 3x3 + BN-ish scale + ReLU (+ optional residual) ----------------
__global__ __launch_bounds__(128) void dwbn_kernel(const float* __restrict__ t,
    const float* __restrict__ w, const float* __restrict__ bias,
    const float* __restrict__ gamma, const float* __restrict__ beta,
    const float* __restrict__ addres, float* __restrict__ out) {
  int p = blockIdx.x;
  int b = p >> 12;
  int ij = p & 4095;
  int i = ij >> 6, j = ij & 63;
  int c = threadIdx.x;
  if (c >= C_) return;
  float acc = bias[c];
#pragma unroll
  for (int di = -1; di <= 1; di++) {
    int ii = i + di;
    if (ii < 0 || ii >= H_) continue;
#pragma unroll
    for (int dj = -1; dj <= 1; dj++) {
      int jj = j + dj;
      if (jj < 0 || jj >= W_) continue;
      acc += t[((size_t)b * L_ + ii * W_ + jj) * C_ + c] * w[c * 9 + (di + 1) * 3 + (dj + 1)];
    }
  }
  float v = acc * (gamma[c] * rsqrtf(1.f + 1e-5f)) + beta[c];
  v = fmaxf(v, 0.f);
  if (addres != nullptr) v += addres[(size_t)p * C_ + c];
  out[(size_t)p * C_ + c] = v;
}

// ---------------- host launcher ----------------
extern "C" void kernel_launch(void* const* d_in, const int* in_sizes, int n_in,
                              void* d_out, int out_size, void* d_ws, size_t ws_size,
                              hipStream_t stream) {
  const float* x         = (const float*)d_in[0];
  const float* norm1_g   = (const float*)d_in[3];
  const float* norm1_b   = (const float*)d_in[4];
  const float* in_proj_w = (const float*)d_in[5];
  const float* conv_w    = (const float*)d_in[6];
  const float* conv_b    = (const float*)d_in[7];
  const float* x_proj_w  = (const float*)d_in[8];
  const float* dt_w      = (const float*)d_in[9];
  const float* dt_b      = (const float*)d_in[10];
  const float* A_logs    = (const float*)d_in[11];
  const float* Ds        = (const float*)d_in[12];
  const float* out_ng    = (const float*)d_in[13];
  const float* out_nb    = (const float*)d_in[14];
  const float* out_proj_w= (const float*)d_in[15];
  const float* norm2_g   = (const float*)d_in[16];
  const float* norm2_b   = (const float*)d_in[17];
  const float* fc1_bw    = (const float*)d_in[18];
  const float* fc1_sw    = (const float*)d_in[19];
  const float* fc2_bw    = (const float*)d_in[20];
  const float* fc2_sw    = (const float*)d_in[21];
  const float* fc3_bw    = (const float*)d_in[22];
  const float* fc3_sw    = (const float*)d_in[23];
  const float* dw1_w     = (const float*)d_in[24];
  const float* dw1_b     = (const float*)d_in[25];
  const float* dw1_g     = (const float*)d_in[26];
  const float* dw1_be    = (const float*)d_in[27];
  const float* dw2_w     = (const float*)d_in[28];
  const float* dw2_b     = (const float*)d_in[29];
  const float* dw2_g     = (const float*)d_in[30];
  const float* dw2_be    = (const float*)d_in[31];
  const float* dw3_w     = (const float*)d_in[32];
  const float* dw3_b     = (const float*)d_in[33];
  const float* dw3_g     = (const float*)d_in[34];
  const float* dw3_be    = (const float*)d_in[35];

  float* ws = (float*)d_ws;
  float* h_buf   = ws;                       // M*96
  float* xin_buf = h_buf + (size_t)M_ * C_;  // M*192  (aliased by aprod after conv)
  float* z_buf   = xin_buf + (size_t)M_ * DI;
  float* imgT    = z_buf + (size_t)M_ * DI;
  float* BsT     = imgT + (size_t)M_ * DI;                 // B*K*L*16
  float* CsT     = BsT + (size_t)B_ * K_ * L_ * NST;
  float* y_pre   = CsT + (size_t)B_ * K_ * L_ * NST;       // M*192
  float* x_res   = y_pre + (size_t)M_ * DI;                // M*96
  float* t_a     = x_res + (size_t)M_ * C_;                // M*96 (hend part 1)
  float* t_b     = t_a + (size_t)M_ * C_;                  // M*96 (hend part 2)
  float* delta   = t_b + (size_t)M_ * C_;                  // B*K*L*DI (50 MB)
  // aliases (lifetimes disjoint):
  float* aprod   = xin_buf;   // B*K*NCH*DI*NST = M*DI floats, xin dead after conv
  float* hend    = t_a;       // B*K*NCH*DI*NST = 2*M*C floats, t_a/t_b used only post-scan

  // 1. LN1
  ln96_kernel<<<M_ / 4, 256, 0, stream>>>(x, norm1_g, norm1_b, h_buf);
  // 2. in_proj -> xin, z
  gemm_in_kernel<<<M_ / 8, 384, 0, stream>>>(h_buf, in_proj_w, xin_buf, z_buf);
  // 3. dwconv + silu -> imgT (NHWC)
  conv_silu_kernel<<<M_, 192, 0, stream>>>(xin_buf, conv_w, conv_b, imgT);
  // 4. x_dbl projections + delta precompute
  xdbl_kernel<<<B_ * K_ * (L_ / 8), 256, 0, stream>>>(imgT, x_proj_w, dt_w, dt_b,
                                                      delta, BsT, CsT);
  // 5. skip-term init
  ypre_init_kernel<<<(M_ * DI) / 256, 256, 0, stream>>>(imgT, Ds, y_pre);
  // 6. chunked selective scan (register-state version)
  scan1_kernel<<<B_ * K_ * NCH, 192, 0, stream>>>(imgT, delta, BsT, A_logs,
                                                  hend, aprod);
  scan_carry_kernel<<<B_ * K_ * DG, 256, 0, stream>>>(hend, aprod);
  scan2_kernel<<<B_ * K_ * NCH, 192, 0, stream>>>(imgT, delta, BsT, CsT, A_logs,
                                                  hend, y_pre);
  // 7. out-norm LN + silu(z) gate (in-place into z)
  ln_mulz_kernel<<<M_ / 4, 256, 0, stream>>>(y_pre, out_ng, out_nb, z_buf);
  // 8. out_proj + residual
  outproj_kernel<<<M_ / 8, 128, 0, stream>>>(z_buf, out_proj_w, x, x_res);
  // 9. LN2
  ln96_kernel<<<M_ / 4, 256, 0, stream>>>(x_res, norm2_g, norm2_b, h_buf);
  // 10. KAN / dw-bn-relu chain
  kan_kernel<<<M_ / 8, 128, 0, stream>>>(h_buf, fc1_bw, fc1_sw, t_a);
  dwbn_kernel<<<M_, 128, 0, stream>>>(t_a, dw1_w, dw1_b, dw1_g, dw1_be, nullptr, t_b);
  kan_kernel<<<M_ / 8, 128, 0, stream>>>(t_b, fc2_bw, fc2_sw, t_a);
  dwbn_kernel<<<M_, 128, 0, stream>>>(t_a, dw2_w, dw2_b, dw2_g, dw2_be, nullptr, t_b);
  kan_kernel<<<M_ / 8, 128, 0, stream>>>(t_b, fc3_bw, fc3_sw, t_a);
  dwbn_kernel<<<M_, 128, 0, stream>>>(t_a, dw3_w, dw3_b, dw3_g, dw3_be, x_res, (float*)d_out);
}

// Round 4
// 702.842 us; speedup vs baseline: 6.1364x; 1.3390x over previous
//
#include <hip/hip_runtime.h>
#include <math.h>

// Problem constants (fixed shapes from setup_inputs)
constexpr int B_  = 4;
constexpr int H_  = 64;
constexpr int W_  = 64;
constexpr int C_  = 96;
constexpr int L_  = H_ * W_;        // 4096
constexpr int DI  = 192;            // 2*C
constexpr int K_  = 4;
constexpr int NST = 16;
constexpr int R_  = 6;
constexpr int M_  = B_ * L_;        // 16384 rows

// chunked-scan params
constexpr int NCH = 64;             // number of chunks along L
constexpr int CL  = 64;             // chunk length (NCH*CL == L_)
constexpr int DG  = DI / 16;        // 12 d-groups of 16 (carry kernel tiling)

// KAN GEMM params
constexpr int KANK = 864;           // 96 silu + 96*8 spline features
constexpr int KLAY = 96 * KANK;     // 82944 weights per layer

typedef __attribute__((ext_vector_type(8))) short short8;
typedef __attribute__((ext_vector_type(4))) float floatx4;

// ---------------- helpers ----------------
__device__ __forceinline__ float wave_sum64(float v) {
#pragma unroll
  for (int off = 1; off < 64; off <<= 1) v += __shfl_xor(v, off, 64);
  return v;
}

// spatial position read/written by direction k at scan step l
__device__ __forceinline__ int pos_kl(int k, int l) {
  int ll = (k >= 2) ? (L_ - 1 - l) : l;
  int i = ll & 63;      // row
  int j = ll >> 6;      // diag index
  int col = ((k & 1) == 0) ? ((i + j) & 63) : ((j - i) & 63);
  return (i << 6) + col;
}

__device__ __forceinline__ float silu_f(float x) {
  return x / (1.f + __expf(-x));
}

__device__ __forceinline__ float softplus_f(float s) {
  return fmaxf(s, 0.f) + log1pf(__expf(-fabsf(s)));
}

__device__ __forceinline__ unsigned short f2bf(float f) {
  unsigned u = __float_as_uint(f);
  unsigned r = (u + 0x7FFFu + ((u >> 16) & 1u)) >> 16;
  return (unsigned short)r;
}

// compute the 8 cubic B-spline bases for scalar x (grid g_i = 0.4i - 2.2)
__device__ __forceinline__ void spline8(float x, float* bb /*len 11*/) {
#pragma unroll
  for (int i2 = 0; i2 < 11; i2++) {
    float g0 = 0.4f * i2 - 2.2f;
    float g1 = 0.4f * i2 - 1.8f;
    bb[i2] = (x >= g0 && x < g1) ? 1.f : 0.f;
  }
#pragma unroll
  for (int k2 = 1; k2 <= 3; k2++) {
    float invd = 1.f / (0.4f * k2);
#pragma unroll
    for (int i2 = 0; i2 + k2 < 11; i2++) {
      float gi   = 0.4f * i2 - 2.2f;
      float gik1 = 0.4f * (i2 + k2 + 1) - 2.2f;
      bb[i2] = (x - gi) * invd * bb[i2] + (gik1 - x) * invd * bb[i2 + 1];
    }
  }
}

// ---------------- LN over C=96, one wave per row ----------------
__global__ __launch_bounds__(256) void ln96_kernel(const float* __restrict__ in,
    const float* __restrict__ g, const float* __restrict__ b,
    float* __restrict__ out) {
  int wave = blockIdx.x * 4 + (threadIdx.x >> 6);
  int lane = threadIdx.x & 63;
  const float* rp = in + (size_t)wave * C_;
  float v0 = rp[lane];
  float v1 = (lane < C_ - 64) ? rp[lane + 64] : 0.f;
  float s  = wave_sum64(v0 + v1);
  float s2 = wave_sum64(v0 * v0 + v1 * v1);
  float mean = s * (1.f / C_);
  float var  = s2 * (1.f / C_) - mean * mean;
  float inv  = rsqrtf(var + 1e-5f);
  float* op = out + (size_t)wave * C_;
  op[lane] = (v0 - mean) * inv * g[lane] + b[lane];
  if (lane < C_ - 64) op[lane + 64] = (v1 - mean) * inv * g[lane + 64] + b[lane + 64];
}

// ---------------- in_proj: xz = h @ W^T, W (384,96); split into xin/z ----------------
__global__ __launch_bounds__(384) void gemm_in_kernel(const float* __restrict__ h,
    const float* __restrict__ w, float* __restrict__ xin, float* __restrict__ z) {
  __shared__ float hs[8][C_];
  int row0 = blockIdx.x * 8;
  for (int t = threadIdx.x; t < 8 * C_; t += 384)
    hs[t / C_][t % C_] = h[(size_t)(row0 + t / C_) * C_ + (t % C_)];
  __syncthreads();
  int j = threadIdx.x;  // 0..383
  float acc[8];
#pragma unroll
  for (int r = 0; r < 8; r++) acc[r] = 0.f;
  const float* wr = w + (size_t)j * C_;
  for (int c = 0; c < C_; c++) {
    float wv = wr[c];
#pragma unroll
    for (int r = 0; r < 8; r++) acc[r] += wv * hs[r][c];
  }
#pragma unroll
  for (int r = 0; r < 8; r++) {
    size_t row = row0 + r;
    if (j < DI) xin[row * DI + j] = acc[r];
    else        z[row * DI + (j - DI)] = acc[r];
  }
}

// ---------------- depthwise 3x3 conv (NHWC) + SiLU ----------------
__global__ __launch_bounds__(192) void conv_silu_kernel(const float* __restrict__ xin,
    const float* __restrict__ cw, const float* __restrict__ cb, float* __restrict__ imgT) {
  int p = blockIdx.x;          // b*L + i*W + j
  int b = p >> 12;
  int ij = p & 4095;
  int i = ij >> 6, j = ij & 63;
  int c = threadIdx.x;
  float acc = cb[c];
#pragma unroll
  for (int di = -1; di <= 1; di++) {
    int ii = i + di;
    if (ii < 0 || ii >= H_) continue;
#pragma unroll
    for (int dj = -1; dj <= 1; dj++) {
      int jj = j + dj;
      if (jj < 0 || jj >= W_) continue;
      acc += xin[((size_t)b * L_ + ii * W_ + jj) * DI + c] * cw[c * 9 + (di + 1) * 3 + (dj + 1)];
    }
  }
  imgT[(size_t)p * DI + c] = silu_f(acc);
}

// ---------------- x_dbl projections -> delta (B,K,L,DI), BsT/CsT (B,K,L,16) ----------------
__global__ __launch_bounds__(256) void xdbl_kernel(const float* __restrict__ imgT,
    const float* __restrict__ xpw, const float* __restrict__ dtw,
    const float* __restrict__ dtb, float* __restrict__ delta,
    float* __restrict__ BsT, float* __restrict__ CsT) {
  __shared__ float xs[8][193];   // pad to break bank conflicts
  __shared__ float dts_s[8][6];
  int blk = blockIdx.x;          // b*K*(L/8) + k*(L/8) + lt
  int lt = blk % (L_ / 8);
  int bk = blk / (L_ / 8);
  int k = bk % K_, b = bk / K_;
  int l0 = lt * 8;
  for (int t = threadIdx.x; t < 8 * DI; t += 256) {
    int li = t / DI, d = t % DI;
    xs[li][d] = imgT[(size_t)b * L_ * DI + (size_t)pos_kl(k, l0 + li) * DI + d];
  }
  __syncthreads();
  for (int t = threadIdx.x; t < 8 * 38; t += 256) {
    int li = t & 7, c = t >> 3;
    const float* wr = xpw + (size_t)(k * 38 + c) * DI;
    float acc = 0.f;
    for (int d = 0; d < DI; d++) acc += xs[li][d] * wr[d];
    size_t base = (size_t)(b * K_ + k) * L_ + (l0 + li);
    if (c < R_)            dts_s[li][c] = acc;
    else if (c < R_ + NST) BsT[base * NST + (c - R_)] = acc;
    else                   CsT[base * NST + (c - R_ - NST)] = acc;
  }
  __syncthreads();
  // delta[b][k][l][d] = softplus(dtw[k,d,:] . dts + dtb[k,d])
  for (int t = threadIdx.x; t < 8 * DI; t += 256) {
    int li = t / DI, d = t % DI;
    float s = dtb[k * DI + d];
    const float* wv = dtw + (size_t)(k * DI + d) * R_;
#pragma unroll
    for (int r = 0; r < R_; r++) s += wv[r] * dts_s[li][r];
    delta[((size_t)(b * K_ + k) * L_ + (l0 + li)) * DI + d] = softplus_f(s);
  }
}

// ---------------- y_pre init: sum_k Ds[k,d] * imgT (skip term) ----------------
__global__ __launch_bounds__(256) void ypre_init_kernel(const float* __restrict__ imgT,
    const float* __restrict__ Ds, float* __restrict__ y_pre) {
  int idx = blockIdx.x * 256 + threadIdx.x;
  int d = idx % DI;
  float ds = Ds[d] + Ds[DI + d] + Ds[2 * DI + d] + Ds[3 * DI + d];
  y_pre[idx] = imgT[idx] * ds;
}

// ---------------- chunked scan pass 1: register-state local scan from h=0 ----------------
// grid: ((b*K+k)*NCH + c) ; block 192 threads = one per channel d; 16 states/thread
__global__ __launch_bounds__(192) void scan1_kernel(const float* __restrict__ imgT,
    const float* __restrict__ delta, const float* __restrict__ BsT,
    const float* __restrict__ A_logs, float* __restrict__ hend,
    float* __restrict__ aprod) {
  __shared__ float bs_s[CL][NST];
  int blk = blockIdx.x;
  int c = blk % NCH;
  int tmp = blk / NCH;
  int k = tmp % K_, b = tmp / K_;
  int l0 = c * CL;
  int d = threadIdx.x;
  const float* img_b  = imgT  + (size_t)b * L_ * DI;
  const float* del_bk = delta + (size_t)(b * K_ + k) * L_ * DI;
  const float* Bs_bk  = BsT   + (size_t)(b * K_ + k) * L_ * NST + (size_t)l0 * NST;
  for (int t = threadIdx.x; t < CL * NST; t += 192)
    bs_s[t >> 4][t & 15] = Bs_bk[t];
  float A[NST];
  {
    const float* ap = A_logs + (size_t)(k * DI + d) * NST;
#pragma unroll
    for (int n = 0; n < NST; n++) A[n] = -__expf(ap[n]);
  }
  __syncthreads();
  float h[NST];
#pragma unroll
  for (int n = 0; n < NST; n++) h[n] = 0.f;
  float sum_dlt = 0.f;
  // software prefetch of u/delta (coalesced over d)
  float u   = img_b[(size_t)pos_kl(k, l0) * DI + d];
  float dlt = del_bk[(size_t)l0 * DI + d];
  for (int l = 0; l < CL; l++) {
    float uc = u, dc = dlt;
    if (l + 1 < CL) {
      int pn = pos_kl(k, l0 + l + 1);
      u   = img_b[(size_t)pn * DI + d];
      dlt = del_bk[(size_t)(l0 + l + 1) * DI + d];
    }
    float du = dc * uc;
    sum_dlt += dc;
#pragma unroll
    for (int n = 0; n < NST; n++) {
      float dA = __expf(dc * A[n]);
      h[n] = dA * h[n] + du * bs_s[l][n];
    }
  }
  size_t idx = (((size_t)(b * K_ + k) * NCH + c) * DI + d) * NST;
  float4* hp  = (float4*)(hend + idx);
  float4* app = (float4*)(aprod + idx);
#pragma unroll
  for (int q = 0; q < 4; q++) {
    hp[q]  = make_float4(h[4 * q], h[4 * q + 1], h[4 * q + 2], h[4 * q + 3]);
    app[q] = make_float4(__expf(A[4 * q] * sum_dlt), __expf(A[4 * q + 1] * sum_dlt),
                         __expf(A[4 * q + 2] * sum_dlt), __expf(A[4 * q + 3] * sum_dlt));
  }
}

// ---------------- carry sweep over chunks (in-place: hend becomes carry_in) ----------------
// grid: (b*K+k)*DG + dg ; block 256 = 16 d x 16 n
__global__ __launch_bounds__(256) void scan_carry_kernel(float* __restrict__ hend,
    const float* __restrict__ aprod) {
  int blk = blockIdx.x;
  int dg = blk % DG;
  int tmp = blk / DG;
  int k = tmp % K_, b = tmp / K_;
  const size_t DNS = (size_t)DI * NST;
  size_t base = (size_t)(b * K_ + k) * NCH * DNS + (size_t)dg * 16 * NST + threadIdx.x;
  float hv = hend[base], av = aprod[base];
  float carry = 0.f;
  for (int c = 0; c < NCH; c++) {
    size_t idx = base + (size_t)c * DNS;
    float hv_n = 0.f, av_n = 0.f;
    if (c + 1 < NCH) { hv_n = hend[idx + DNS]; av_n = aprod[idx + DNS]; }
    hend[idx] = carry;                 // carry entering chunk c
    carry = av * carry + hv;
    hv = hv_n; av = av_n;
  }
}

// ---------------- chunked scan pass 2: register-state re-scan, emit y ----------------
// grid: ((b*K+k)*NCH + c) ; block 192 threads = one per channel d
__global__ __launch_bounds__(192) void scan2_kernel(const float* __restrict__ imgT,
    const float* __restrict__ delta, const float* __restrict__ BsT,
    const float* __restrict__ CsT, const float* __restrict__ A_logs,
    const float* __restrict__ carry_in, float* __restrict__ y_pre) {
  __shared__ float bs_s[CL][NST];
  __shared__ float cs_s[CL][NST];
  int blk = blockIdx.x;
  int c = blk % NCH;
  int tmp = blk / NCH;
  int k = tmp % K_, b = tmp / K_;
  int l0 = c * CL;
  int d = threadIdx.x;
  const float* img_b  = imgT  + (size_t)b * L_ * DI;
  const float* del_bk = delta + (size_t)(b * K_ + k) * L_ * DI;
  const float* Bs_bk  = BsT   + (size_t)(b * K_ + k) * L_ * NST + (size_t)l0 * NST;
  const float* Cs_bk  = CsT   + (size_t)(b * K_ + k) * L_ * NST + (size_t)l0 * NST;
  for (int t = threadIdx.x; t < CL * NST; t += 192) {
    bs_s[t >> 4][t & 15] = Bs_bk[t];
    cs_s[t >> 4][t & 15] = Cs_bk[t];
  }
  float A[NST];
  {
    const float* ap = A_logs + (size_t)(k * DI + d) * NST;
#pragma unroll
    for (int n = 0; n < NST; n++) A[n] = -__expf(ap[n]);
  }
  float h[NST];
  {
    size_t cidx = (((size_t)(b * K_ + k) * NCH + c) * DI + d) * NST;
    const float4* cp = (const float4*)(carry_in + cidx);
#pragma unroll
    for (int q = 0; q < 4; q++) {
      float4 v = cp[q];
      h[4 * q] = v.x; h[4 * q + 1] = v.y; h[4 * q + 2] = v.z; h[4 * q + 3] = v.w;
    }
  }
  __syncthreads();
  float* yp_b = y_pre + (size_t)b * L_ * DI;
  int pc = pos_kl(k, l0);
  float u   = img_b[(size_t)pc * DI + d];
  float dlt = del_bk[(size_t)l0 * DI + d];
  for (int l = 0; l < CL; l++) {
    float uc = u, dc = dlt;
    int p_cur = pc;
    if (l + 1 < CL) {
      pc = pos_kl(k, l0 + l + 1);
      u   = img_b[(size_t)pc * DI + d];
      dlt = del_bk[(size_t)(l0 + l + 1) * DI + d];
    }
    float du = dc * uc;
    float y = 0.f;
#pragma unroll
    for (int n = 0; n < NST; n++) {
      float dA = __expf(dc * A[n]);
      h[n] = dA * h[n] + du * bs_s[l][n];
      y += h[n] * cs_s[l][n];
    }
    atomicAdd(&yp_b[(size_t)p_cur * DI + d], y);   // coalesced across d
  }
}

// ---------------- LN over Di=192 + multiply by silu(z), in-place into z ----------------
__global__ __launch_bounds__(256) void ln_mulz_kernel(const float* __restrict__ y_pre,
    const float* __restrict__ g, const float* __restrict__ bb, float* __restrict__ z) {
  int wave = blockIdx.x * 4 + (threadIdx.x >> 6);
  int lane = threadIdx.x & 63;
  const float* rp = y_pre + (size_t)wave * DI;
  float v0 = rp[lane], v1 = rp[lane + 64], v2 = rp[lane + 128];
  float s  = wave_sum64(v0 + v1 + v2);
  float s2 = wave_sum64(v0 * v0 + v1 * v1 + v2 * v2);
  float mean = s * (1.f / DI);
  float var  = s2 * (1.f / DI) - mean * mean;
  float inv  = rsqrtf(var + 1e-5f);
  float* zp = z + (size_t)wave * DI;
  float vv[3] = {v0, v1, v2};
#pragma unroll
  for (int q = 0; q < 3; q++) {
    int c = lane + 64 * q;
    float zv = zp[c];
    zp[c] = ((vv[q] - mean) * inv * g[c] + bb[c]) * silu_f(zv);
  }
}

// ---------------- out_proj (96x192) + residual add ----------------
__global__ __launch_bounds__(128) void outproj_kernel(const float* __restrict__ yz,
    const float* __restrict__ opw, const float* __restrict__ x, float* __restrict__ x_res) {
  __shared__ float ys[8][DI];
  int row0 = blockIdx.x * 8;
  for (int t = threadIdx.x; t < 8 * DI; t += 128)
    ys[t / DI][t % DI] = yz[(size_t)(row0 + t / DI) * DI + (t % DI)];
  __syncthreads();
  int j = threadIdx.x;
  if (j < C_) {
    float acc[8];
#pragma unroll
    for (int r = 0; r < 8; r++) acc[r] = 0.f;
    const float* wr = opw + (size_t)j * DI;
    for (int d = 0; d < DI; d++) {
      float wv = wr[d];
#pragma unroll
      for (int r = 0; r < 8; r++) acc[r] += wv * ys[r][d];
    }
#pragma unroll
    for (int r = 0; r < 8; r++) {
      size_t row = row0 + r;
      x_res[row * C_ + j] = x[row * C_ + j] + acc[r];
    }
  }
}

// ---------------- weight prep: pack [bw|sw] per layer into bf16 Wcat[3][96][864] ----------------
__global__ __launch_bounds__(256) void prepw_kernel(const float* __restrict__ bw1,
    const float* __restrict__ sw1, const float* __restrict__ bw2,
    const float* __restrict__ sw2, const float* __restrict__ bw3,
    const float* __restrict__ sw3, unsigned short* __restrict__ wcat) {
  int idx = blockIdx.x * 256 + threadIdx.x;
  if (idx >= 3 * KLAY) return;
  int layer = idx / KLAY, rem = idx % KLAY;
  int j = rem / KANK, k = rem % KANK;
  const float* bw = (layer == 0) ? bw1 : (layer == 1) ? bw2 : bw3;
  const float* sw = (layer == 0) ? sw1 : (layer == 1) ? sw2 : sw3;
  float v = (k < C_) ? bw[j * C_ + k] : sw[j * 768 + (k - C_)];
  wcat[idx] = f2bf(v);
}

// ---------------- KAN linear via bf16 MFMA ----------------
// C[M,96] = A[M,864] x W'[96,864]^T ; A generated on the fly (silu + spline bases)
// block: 128 threads (2 waves), 64-row tile; wave w handles rows w*32..w*32+31
// K chunked 9 x 96 (chunk 0 = silu features, chunks 1..8 = spline features)
__global__ __launch_bounds__(128) void kan_mfma_kernel(const float* __restrict__ in,
    const unsigned short* __restrict__ wl, float* __restrict__ out) {
  __shared__ __align__(16) float x_s[64][100];
  __shared__ __align__(16) unsigned short A_s[64][104];
  __shared__ __align__(16) unsigned short W_s[96][104];
  int row0 = blockIdx.x * 64;
  // stage x tile (64 x 96 fp32), float4-coalesced
  for (int t = threadIdx.x; t < 64 * 24; t += 128) {
    int r = t / 24, c4 = (t % 24) * 4;
    *(float4*)&x_s[r][c4] = *(const float4*)&in[(size_t)(row0 + r) * C_ + c4];
  }
  floatx4 acc[12];
#pragma unroll
  for (int q = 0; q < 12; q++) acc[q] = (floatx4)(0.f);
  int wv = threadIdx.x >> 6;          // 0..1
  int lane = threadIdx.x & 63;
  int mrow = lane & 15, quad = lane >> 4;
  __syncthreads();
  for (int ci = 0; ci < 9; ci++) {
    if (ci) __syncthreads();          // previous chunk's MFMA reads done
    // stage W_s: 96 rows x 96 bf16 (wl row stride 864, col offset ci*96)
    for (int t = threadIdx.x; t < 96 * 12; t += 128) {
      int j = t / 12, u = t % 12;
      *(short8*)&W_s[j][u * 8] =
          *(const short8*)&wl[(size_t)j * KANK + ci * 96 + u * 8];
    }
    // stage A_s: 64 rows x 96 bf16 features
    if (ci == 0) {
      for (int t = threadIdx.x; t < 64 * 48; t += 128) {
        int r = t / 48, k2 = (t % 48) * 2;
        unsigned v = (unsigned)f2bf(silu_f(x_s[r][k2])) |
                     ((unsigned)f2bf(silu_f(x_s[r][k2 + 1])) << 16);
        *(unsigned*)&A_s[r][k2] = v;
      }
    } else {
      int c0 = (ci - 1) * 12;
      for (int t = threadIdx.x; t < 64 * 12; t += 128) {
        int r = t & 63, cl = t >> 6;   // cl 0..11
        float x = x_s[r][c0 + cl];
        float bb[11];
        spline8(x, bb);
        short8 av;
#pragma unroll
        for (int q = 0; q < 8; q++) av[q] = (short)f2bf(bb[q]);
        *(short8*)&A_s[r][cl * 8] = av;
      }
    }
    __syncthreads();
    // MFMA over this chunk: 3 K-steps of 32
#pragma unroll
    for (int ks = 0; ks < 3; ks++) {
      short8 a0 = *(const short8*)&A_s[wv * 32 + mrow][ks * 32 + quad * 8];
      short8 a1 = *(const short8*)&A_s[wv * 32 + 16 + mrow][ks * 32 + quad * 8];
#pragma unroll
      for (int ct = 0; ct < 6; ct++) {
        short8 b = *(const short8*)&W_s[ct * 16 + mrow][ks * 32 + quad * 8];
        acc[ct]     = __builtin_amdgcn_mfma_f32_16x16x32_bf16(a0, b, acc[ct], 0, 0, 0);
        acc[6 + ct] = __builtin_amdgcn_mfma_f32_16x16x32_bf16(a1, b, acc[6 + ct], 0, 0, 0);
      }
    }
  }
  // epilogue: D mapping col = lane&15, row = quad*4 + reg
#pragma unroll
  for (int half = 0; half < 2; half++)
#pragma unroll
    for (int ct = 0; ct < 6; ct++)
#pragma unroll
      for (int rg = 0; rg < 4; rg++) {
        int row = row0 + wv * 32 + half * 16 + quad * 4 + rg;
        out[(size_t)row * C_ + ct * 16 + mrow] = acc[half * 6 + ct][rg];
      }
}

// ---------------- depthwise 3x3 + BN-ish scale + ReLU (+ optional residual) ----------------
__global__ __launch_bounds__(128) void dwbn_kernel(const float* __restrict__ t,
    const float* __restrict__ w, const float* __restrict__ bias,
    const float* __restrict__ gamma, const float* __restrict__ beta,
    const float* __restrict__ addres, float* __restrict__ out) {
  int p = blockIdx.x;
  int b = p >> 12;
  int ij = p & 4095;
  int i = ij >> 6, j = ij & 63;
  int c = threadIdx.x;
  if (c >= C_) return;
  float acc = bias[c];
#pragma unroll
  for (int di = -1; di <= 1; di++) {
    int ii = i + di;
    if (ii < 0 || ii >= H_) continue;
#pragma unroll
    for (int dj = -1; dj <= 1; dj++) {
      int jj = j + dj;
      if (jj < 0 || jj >= W_) continue;
      acc += t[((size_t)b * L_ + ii * W_ + jj) * C_ + c] * w[c * 9 + (di + 1) * 3 + (dj + 1)];
    }
  }
  float v = acc * (gamma[c] * rsqrtf(1.f + 1e-5f)) + beta[c];
  v = fmaxf(v, 0.f);
  if (addres != nullptr) v += addres[(size_t)p * C_ + c];
  out[(size_t)p * C_ + c] = v;
}

// ---------------- host launcher ----------------
extern "C" void kernel_launch(void* const* d_in, const int* in_sizes, int n_in,
                              void* d_out, int out_size, void* d_ws, size_t ws_size,
                              hipStream_t stream) {
  const float* x         = (const float*)d_in[0];
  const float* norm1_g   = (const float*)d_in[3];
  const float* norm1_b   = (const float*)d_in[4];
  const float* in_proj_w = (const float*)d_in[5];
  const float* conv_w    = (const float*)d_in[6];
  const float* conv_b    = (const float*)d_in[7];
  const float* x_proj_w  = (const float*)d_in[8];
  const float* dt_w      = (const float*)d_in[9];
  const float* dt_b      = (const float*)d_in[10];
  const float* A_logs    = (const float*)d_in[11];
  const float* Ds        = (const float*)d_in[12];
  const float* out_ng    = (const float*)d_in[13];
  const float* out_nb    = (const float*)d_in[14];
  const float* out_proj_w= (const float*)d_in[15];
  const float* norm2_g   = (const float*)d_in[16];
  const float* norm2_b   = (const float*)d_in[17];
  const float* fc1_bw    = (const float*)d_in[18];
  const float* fc1_sw    = (const float*)d_in[19];
  const float* fc2_bw    = (const float*)d_in[20];
  const float* fc2_sw    = (const float*)d_in[21];
  const float* fc3_bw    = (const float*)d_in[22];
  const float* fc3_sw    = (const float*)d_in[23];
  const float* dw1_w     = (const float*)d_in[24];
  const float* dw1_b     = (const float*)d_in[25];
  const float* dw1_g     = (const float*)d_in[26];
  const float* dw1_be    = (const float*)d_in[27];
  const float* dw2_w     = (const float*)d_in[28];
  const float* dw2_b     = (const float*)d_in[29];
  const float* dw2_g     = (const float*)d_in[30];
  const float* dw2_be    = (const float*)d_in[31];
  const float* dw3_w     = (const float*)d_in[32];
  const float* dw3_b     = (const float*)d_in[33];
  const float* dw3_g     = (const float*)d_in[34];
  const float* dw3_be    = (const float*)d_in[35];

  float* ws = (float*)d_ws;
  float* h_buf   = ws;                       // M*96
  float* xin_buf = h_buf + (size_t)M_ * C_;  // M*192  (aliased by aprod after conv)
  float* z_buf   = xin_buf + (size_t)M_ * DI;
  float* imgT    = z_buf + (size_t)M_ * DI;
  float* BsT     = imgT + (size_t)M_ * DI;                 // B*K*L*16
  float* CsT     = BsT + (size_t)B_ * K_ * L_ * NST;
  float* y_pre   = CsT + (size_t)B_ * K_ * L_ * NST;       // M*192
  float* x_res   = y_pre + (size_t)M_ * DI;                // M*96
  float* t_a     = x_res + (size_t)M_ * C_;                // M*96 (hend part 1)
  float* t_b     = t_a + (size_t)M_ * C_;                  // M*96 (hend part 2)
  float* delta   = t_b + (size_t)M_ * C_;                  // B*K*L*DI (50 MB)
  // aliases (lifetimes disjoint):
  float* aprod   = xin_buf;   // scan scratch; xin dead after conv
  float* hend    = t_a;       // scan scratch; t_a/t_b used only post-scan
  unsigned short* wcat = (unsigned short*)BsT;  // bf16 KAN weights; BsT dead after scan2

  // 1. LN1
  ln96_kernel<<<M_ / 4, 256, 0, stream>>>(x, norm1_g, norm1_b, h_buf);
  // 2. in_proj -> xin, z
  gemm_in_kernel<<<M_ / 8, 384, 0, stream>>>(h_buf, in_proj_w, xin_buf, z_buf);
  // 3. dwconv + silu -> imgT (NHWC)
  conv_silu_kernel<<<M_, 192, 0, stream>>>(xin_buf, conv_w, conv_b, imgT);
  // 4. x_dbl projections + delta precompute
  xdbl_kernel<<<B_ * K_ * (L_ / 8), 256, 0, stream>>>(imgT, x_proj_w, dt_w, dt_b,
                                                      delta, BsT, CsT);
  // 5. skip-term init
  ypre_init_kernel<<<(M_ * DI) / 256, 256, 0, stream>>>(imgT, Ds, y_pre);
  // 6. chunked selective scan (register-state version)
  scan1_kernel<<<B_ * K_ * NCH, 192, 0, stream>>>(imgT, delta, BsT, A_logs,
                                                  hend, aprod);
  scan_carry_kernel<<<B_ * K_ * DG, 256, 0, stream>>>(hend, aprod);
  scan2_kernel<<<B_ * K_ * NCH, 192, 0, stream>>>(imgT, delta, BsT, CsT, A_logs,
                                                  hend, y_pre);
  // 6b. pack KAN weights to bf16 (BsT region is dead from here on)
  prepw_kernel<<<(3 * KLAY + 255) / 256, 256, 0, stream>>>(fc1_bw, fc1_sw, fc2_bw,
                                                           fc2_sw, fc3_bw, fc3_sw, wcat);
  // 7. out-norm LN + silu(z) gate (in-place into z)
  ln_mulz_kernel<<<M_ / 4, 256, 0, stream>>>(y_pre, out_ng, out_nb, z_buf);
  // 8. out_proj + residual
  outproj_kernel<<<M_ / 8, 128, 0, stream>>>(z_buf, out_proj_w, x, x_res);
  // 9. LN2
  ln96_kernel<<<M_ / 4, 256, 0, stream>>>(x_res, norm2_g, norm2_b, h_buf);
  // 10. KAN (bf16 MFMA) / dw-bn-relu chain
  kan_mfma_kernel<<<M_ / 64, 128, 0, stream>>>(h_buf, wcat, t_a);
  dwbn_kernel<<<M_, 128, 0, stream>>>(t_a, dw1_w, dw1_b, dw1_g, dw1_be, nullptr, t_b);
  kan_mfma_kernel<<<M_ / 64, 128, 0, stream>>>(t_b, wcat + KLAY, t_a);
  dwbn_kernel<<<M_, 128, 0, stream>>>(t_a, dw2_w, dw2_b, dw2_g, dw2_be, nullptr, t_b);
  kan_mfma_kernel<<<M_ / 64, 128, 0, stream>>>(t_b, wcat + 2 * KLAY, t_a);
  dwbn_kernel<<<M_, 128, 0, stream>>>(t_a, dw3_w, dw3_b, dw3_g, dw3_be, x_res, (float*)d_out);
}